// Round 1
// baseline (1303.048 us; speedup 1.0000x reference)
//
#include <hip/hip_runtime.h>

#define NF0 5
#define F1 320
#define F2 160
#define F3 80

// ---------------- edge-index width detection + conversion ----------------

__global__ void k_detect(const unsigned int* ei32, int npairs, int* flag) {
    __shared__ int ok;
    if (threadIdx.x == 0) ok = 1;
    __syncthreads();
    for (int i = threadIdx.x; i < npairs; i += blockDim.x) {
        if (ei32[2 * i + 1] != 0u) ok = 0;   // benign race: everyone writes 0
    }
    __syncthreads();
    if (threadIdx.x == 0) *flag = ok;        // 1 => int64 storage, 0 => int32
}

__global__ void k_convert(const void* ei, int E, const int* flag, int* srcv, int* dstv) {
    int e = blockIdx.x * blockDim.x + threadIdx.x;
    if (e >= E) return;
    if (*flag) {
        const long long* p = (const long long*)ei;
        srcv[e] = (int)p[e];
        dstv[e] = (int)p[E + e];
    } else {
        const int* p = (const int*)ei;
        srcv[e] = p[e];
        dstv[e] = p[E + e];
    }
}

// ---------------- degree / norm ----------------

__global__ void k_deg(const int* dstv, const float* ew, float* deg, int E) {
    int e = blockIdx.x * blockDim.x + threadIdx.x;
    if (e < E) atomicAdd(&deg[dstv[e]], ew[e]);
}

__global__ void k_dinv(float* deg, int N) {
    int i = blockIdx.x * blockDim.x + threadIdx.x;
    if (i < N) {
        float d = deg[i] + 1.0f;   // self-loop weight 1; always > 0
        deg[i] = rsqrtf(d);
    }
}

__global__ void k_norm(const int* srcv, const int* dstv, const float* ew,
                       const float* dinv, float* norm, int E) {
    int e = blockIdx.x * blockDim.x + threadIdx.x;
    if (e < E) norm[e] = dinv[srcv[e]] * ew[e] * dinv[dstv[e]];
}

// ---------------- folded weights: W2c = W2 @ We, bc = b2 @ We + be ----------------

__global__ void k_w2c(const float* __restrict__ W2, const float* __restrict__ We,
                      float* __restrict__ W2c) {
    int o = blockIdx.x * blockDim.x + threadIdx.x;
    if (o >= F1 * F3) return;
    int k = o / F3, j = o % F3;
    float s = 0.f;
    for (int m = 0; m < F2; ++m) s += W2[k * F2 + m] * We[m * F3 + j];
    W2c[o] = s;
}

__global__ void k_bc(const float* b2, const float* We, const float* be, float* bc) {
    int j = threadIdx.x;
    if (j >= F3) return;
    float s = be[j];
    for (int k = 0; k < F2; ++k) s += b2[k] * We[k * F3 + j];
    bc[j] = s;
}

// ---------------- conv1 aggregation on raw x (5 features) ----------------

__global__ void k_selfinit1(const float* __restrict__ x, const float* __restrict__ dinv,
                            float* __restrict__ agg1, int N) {
    int idx = blockIdx.x * blockDim.x + threadIdx.x;
    if (idx >= N * NF0) return;
    int i = idx / NF0;
    float di = dinv[i];
    agg1[idx] = x[idx] * di * di;
}

__global__ void k_agg1(const int* __restrict__ srcv, const int* __restrict__ dstv,
                       const float* __restrict__ norm, const float* __restrict__ x,
                       float* __restrict__ agg1, int E) {
    int e = blockIdx.x * blockDim.x + threadIdx.x;
    if (e >= E) return;
    int s = srcv[e], d = dstv[e];
    float w = norm[e];
    #pragma unroll
    for (int f = 0; f < NF0; ++f)
        atomicAdd(&agg1[d * NF0 + f], x[s * NF0 + f] * w);
}

// ---------------- fused per-node transform: g = relu(agg1@W1 + b1) @ W2c ----------------

__global__ __launch_bounds__(256) void k_node(const float* __restrict__ agg1,
                                              const float* __restrict__ W1,
                                              const float* __restrict__ b1,
                                              const float* __restrict__ W2c,
                                              float* __restrict__ g, int N) {
    __shared__ float t_lds[32][F1 + 4];   // +4 pad: break 320%32==0 bank aliasing
    int tid = threadIdx.x;
    int nb = blockIdx.x * 32;

    // Phase 1: t = relu(agg1 @ W1 + b1) for 32 nodes, 8 threads per node
    {
        int nl = tid >> 3;      // node local 0..31
        int ko = tid & 7;       // k offset 0..7
        int node = nb + nl;
        float a0 = 0.f, a1 = 0.f, a2 = 0.f, a3 = 0.f, a4 = 0.f;
        if (node < N) {
            const float* ap = agg1 + (size_t)node * NF0;
            a0 = ap[0]; a1 = ap[1]; a2 = ap[2]; a3 = ap[3]; a4 = ap[4];
        }
        #pragma unroll
        for (int kk = 0; kk < 40; ++kk) {
            int k = ko + (kk << 3);
            float v = b1[k];
            v += a0 * W1[k];
            v += a1 * W1[F1 + k];
            v += a2 * W1[2 * F1 + k];
            v += a3 * W1[3 * F1 + k];
            v += a4 * W1[4 * F1 + k];
            t_lds[nl][k] = fmaxf(v, 0.f);
        }
    }
    __syncthreads();

    // Phase 2: g = t @ W2c ; wave handles 8 nodes, lane l -> column l (and 64+l for l<16)
    int wv = tid >> 6;
    int lane = tid & 63;
    float acc0[8] = {0.f, 0.f, 0.f, 0.f, 0.f, 0.f, 0.f, 0.f};
    float acc1[8] = {0.f, 0.f, 0.f, 0.f, 0.f, 0.f, 0.f, 0.f};
    const float* wp0 = W2c + lane;
    const float* wp1 = W2c + 64 + (lane < 16 ? lane : 0);
    int row0 = wv * 8;

    for (int k = 0; k < F1; k += 4) {
        float wa0 = wp0[(k + 0) * F3];
        float wa1 = wp0[(k + 1) * F3];
        float wa2 = wp0[(k + 2) * F3];
        float wa3 = wp0[(k + 3) * F3];
        float wb0 = wp1[(k + 0) * F3];
        float wb1 = wp1[(k + 1) * F3];
        float wb2 = wp1[(k + 2) * F3];
        float wb3 = wp1[(k + 3) * F3];
        #pragma unroll
        for (int nn = 0; nn < 8; ++nn) {
            const float4 t4 = *(const float4*)&t_lds[row0 + nn][k];
            acc0[nn] += t4.x * wa0 + t4.y * wa1 + t4.z * wa2 + t4.w * wa3;
            acc1[nn] += t4.x * wb0 + t4.y * wb1 + t4.z * wb2 + t4.w * wb3;
        }
    }

    int nodebase = nb + row0;
    #pragma unroll
    for (int nn = 0; nn < 8; ++nn) {
        int node = nodebase + nn;
        if (node < N) {
            g[(size_t)node * F3 + lane] = acc0[nn];
            if (lane < 16) g[(size_t)node * F3 + 64 + lane] = acc1[nn];
        }
    }
}

// ---------------- conv2 aggregation (80 features) straight into d_out ----------------

__global__ void k_selfinit2(const float* __restrict__ g, const float* __restrict__ dinv,
                            const float* __restrict__ bc, float* __restrict__ out, int N) {
    int idx = blockIdx.x * blockDim.x + threadIdx.x;   // over N*20 float4 chunks
    if (idx >= N * (F3 / 4)) return;
    int i = idx / (F3 / 4), c = idx % (F3 / 4);
    float di = dinv[i];
    float s = di * di;
    float4 v = ((const float4*)g)[idx];
    float4 b = ((const float4*)bc)[c];
    float4 o;
    o.x = v.x * s + b.x;
    o.y = v.y * s + b.y;
    o.z = v.z * s + b.z;
    o.w = v.w * s + b.w;
    ((float4*)out)[idx] = o;
}

__global__ void k_agg2(const int* __restrict__ srcv, const int* __restrict__ dstv,
                       const float* __restrict__ norm, const float* __restrict__ g,
                       float* __restrict__ out, int E) {
    int t = blockIdx.x * blockDim.x + threadIdx.x;     // E * 20 threads
    if (t >= E * (F3 / 4)) return;
    int e = t / (F3 / 4), c = t % (F3 / 4);
    int s = srcv[e], d = dstv[e];
    float w = norm[e];
    float4 v = ((const float4*)g)[(size_t)s * (F3 / 4) + c];
    float* op = out + (size_t)d * F3 + c * 4;
    atomicAdd(op + 0, v.x * w);
    atomicAdd(op + 1, v.y * w);
    atomicAdd(op + 2, v.z * w);
    atomicAdd(op + 3, v.w * w);
}

// ---------------- launch ----------------

static inline size_t align256(size_t x) { return (x + 255) & ~(size_t)255; }

extern "C" void kernel_launch(void* const* d_in, const int* in_sizes, int n_in,
                              void* d_out, int out_size, void* d_ws, size_t ws_size,
                              hipStream_t stream) {
    const float* x  = (const float*)d_in[0];
    const void*  ei = d_in[1];
    const float* ew = (const float*)d_in[2];
    const float* W1 = (const float*)d_in[3];
    const float* b1 = (const float*)d_in[4];
    const float* W2 = (const float*)d_in[5];
    const float* b2 = (const float*)d_in[6];
    const float* We = (const float*)d_in[7];
    const float* be = (const float*)d_in[8];
    float* out = (float*)d_out;

    int N = in_sizes[0] / NF0;
    int E = in_sizes[2];

    char* p = (char*)d_ws;
    auto alloc = [&](size_t bytes) { char* r = p; p += align256(bytes); return r; };
    int*   flag = (int*)  alloc(4);
    int*   srcv = (int*)  alloc((size_t)E * 4);
    int*   dstv = (int*)  alloc((size_t)E * 4);
    float* dinv = (float*)alloc((size_t)N * 4);
    float* norm = (float*)alloc((size_t)E * 4);
    float* agg1 = (float*)alloc((size_t)N * NF0 * 4);
    float* W2c  = (float*)alloc((size_t)F1 * F3 * 4);
    float* bc   = (float*)alloc((size_t)F3 * 4);
    float* g    = (float*)alloc((size_t)N * F3 * 4);

    int eb = (E + 255) / 256;
    int npairs = E < 2048 ? E : 2048;

    k_detect<<<1, 256, 0, stream>>>((const unsigned int*)ei, npairs, flag);
    k_convert<<<eb, 256, 0, stream>>>(ei, E, flag, srcv, dstv);

    hipMemsetAsync(dinv, 0, (size_t)N * 4, stream);
    k_deg<<<eb, 256, 0, stream>>>(dstv, ew, dinv, E);
    k_dinv<<<(N + 255) / 256, 256, 0, stream>>>(dinv, N);
    k_norm<<<eb, 256, 0, stream>>>(srcv, dstv, ew, dinv, norm, E);

    k_w2c<<<(F1 * F3 + 255) / 256, 256, 0, stream>>>(W2, We, W2c);
    k_bc<<<1, 128, 0, stream>>>(b2, We, be, bc);

    k_selfinit1<<<(N * NF0 + 255) / 256, 256, 0, stream>>>(x, dinv, agg1, N);
    k_agg1<<<eb, 256, 0, stream>>>(srcv, dstv, norm, x, agg1, E);

    k_node<<<(N + 31) / 32, 256, 0, stream>>>(agg1, W1, b1, W2c, g, N);

    k_selfinit2<<<(N * (F3 / 4) + 255) / 256, 256, 0, stream>>>(g, dinv, bc, out, N);
    k_agg2<<<(E * (F3 / 4) + 255) / 256, 256, 0, stream>>>(srcv, dstv, norm, g, out, E);
}

// Round 2
// 401.218 us; speedup vs baseline: 3.2477x; 3.2477x over previous
//
#include <hip/hip_runtime.h>

#define NF0 5
#define F1 320
#define F2 160
#define F3 80
#define C4 (F3 / 4)   // 20 float4 chunks per node

// ---------------- edge-index width detection + conversion ----------------

__global__ void k_detect(const unsigned int* ei32, int npairs, int* flag) {
    __shared__ int ok;
    if (threadIdx.x == 0) ok = 1;
    __syncthreads();
    for (int i = threadIdx.x; i < npairs; i += blockDim.x) {
        if (ei32[2 * i + 1] != 0u) ok = 0;   // benign race: everyone writes 0
    }
    __syncthreads();
    if (threadIdx.x == 0) *flag = ok;        // 1 => int64 storage, 0 => int32
}

__global__ void k_convert(const void* ei, int E, const int* flag, int* srcv, int* dstv) {
    int e = blockIdx.x * blockDim.x + threadIdx.x;
    if (e >= E) return;
    if (*flag) {
        const long long* p = (const long long*)ei;
        srcv[e] = (int)p[e];
        dstv[e] = (int)p[E + e];
    } else {
        const int* p = (const int*)ei;
        srcv[e] = p[e];
        dstv[e] = p[E + e];
    }
}

// ---------------- degree (float) + in-degree count (int) ----------------

__global__ void k_hist(const int* __restrict__ dstv, const float* __restrict__ ew,
                       float* __restrict__ deg, int* __restrict__ cnt, int E) {
    int e = blockIdx.x * blockDim.x + threadIdx.x;
    if (e >= E) return;
    int d = dstv[e];
    atomicAdd(&deg[d], ew[e]);
    atomicAdd(&cnt[d], 1);
}

__global__ void k_dinv(float* deg, int N) {
    int i = blockIdx.x * blockDim.x + threadIdx.x;
    if (i < N) {
        float d = deg[i] + 1.0f;   // self-loop weight 1; always > 0
        deg[i] = rsqrtf(d);
    }
}

// ---------------- exclusive scan of cnt -> rowoff (3 kernels) ----------------

__global__ void k_scanA(const int* __restrict__ cnt, int* __restrict__ bsum, int N) {
    __shared__ int s[256];
    int t = threadIdx.x;
    int gid = blockIdx.x * 256 + t;
    s[t] = gid < N ? cnt[gid] : 0;
    __syncthreads();
    for (int o = 128; o > 0; o >>= 1) {
        if (t < o) s[t] += s[t + o];
        __syncthreads();
    }
    if (t == 0) bsum[blockIdx.x] = s[0];
}

__global__ void k_scanB(int* bsum, int nb, int* rowoff, int N, int E) {
    __shared__ int s[512];
    int t = threadIdx.x;
    int v = t < nb ? bsum[t] : 0;
    s[t] = v;
    __syncthreads();
    for (int o = 1; o < 512; o <<= 1) {
        int a = (t >= o) ? s[t - o] : 0;
        __syncthreads();
        s[t] += a;
        __syncthreads();
    }
    if (t < nb) bsum[t] = s[t] - v;  // exclusive block offsets
    if (t == 0) rowoff[N] = E;
}

__global__ void k_scanC(const int* __restrict__ cnt, const int* __restrict__ bsum_ex,
                        int* __restrict__ rowoff, int* __restrict__ cursor, int N) {
    __shared__ int s[256];
    int t = threadIdx.x;
    int gid = blockIdx.x * 256 + t;
    int v = gid < N ? cnt[gid] : 0;
    s[t] = v;
    __syncthreads();
    for (int o = 1; o < 256; o <<= 1) {
        int a = (t >= o) ? s[t - o] : 0;
        __syncthreads();
        s[t] += a;
        __syncthreads();
    }
    if (gid < N) {
        int ex = bsum_ex[blockIdx.x] + s[t] - v;
        rowoff[gid] = ex;
        cursor[gid] = ex;
    }
}

// ---------------- scatter edges into CSR (by dst), fold norm ----------------

__global__ void k_scatter(const int* __restrict__ srcv, const int* __restrict__ dstv,
                          const float* __restrict__ ew, const float* __restrict__ dinv,
                          int* __restrict__ cursor, int* __restrict__ csr_src,
                          float* __restrict__ csr_w, int E) {
    int e = blockIdx.x * blockDim.x + threadIdx.x;
    if (e >= E) return;
    int s = srcv[e], d = dstv[e];
    int pos = atomicAdd(&cursor[d], 1);
    csr_src[pos] = s;
    csr_w[pos] = dinv[s] * ew[e] * dinv[d];
}

// ---------------- folded weights: W2c = W2 @ We, bc = b2 @ We + be ----------------

__global__ void k_w2c(const float* __restrict__ W2, const float* __restrict__ We,
                      float* __restrict__ W2c) {
    int o = blockIdx.x * blockDim.x + threadIdx.x;
    if (o >= F1 * F3) return;
    int k = o / F3, j = o % F3;
    float s = 0.f;
    for (int m = 0; m < F2; ++m) s += W2[k * F2 + m] * We[m * F3 + j];
    W2c[o] = s;
}

__global__ void k_bc(const float* b2, const float* We, const float* be, float* bc) {
    int j = threadIdx.x;
    if (j >= F3) return;
    float s = be[j];
    for (int k = 0; k < F2; ++k) s += b2[k] * We[k * F3 + j];
    bc[j] = s;
}

// ---------------- conv1 aggregation via CSR gather (5 features, self folded) ----------------

__global__ void k_aggA(const float* __restrict__ x, const float* __restrict__ dinv,
                       const int* __restrict__ rowoff, const int* __restrict__ csr_src,
                       const float* __restrict__ csr_w, float* __restrict__ agg1, int N) {
    int i = blockIdx.x * blockDim.x + threadIdx.x;
    if (i >= N) return;
    float di = dinv[i];
    float sc = di * di;
    const float* xp = x + (size_t)i * NF0;
    float a0 = xp[0] * sc, a1 = xp[1] * sc, a2 = xp[2] * sc, a3 = xp[3] * sc, a4 = xp[4] * sc;
    int b = rowoff[i], en = rowoff[i + 1];
    for (int j = b; j < en; ++j) {
        int s = csr_src[j];
        float w = csr_w[j];
        const float* sp = x + (size_t)s * NF0;
        a0 += sp[0] * w; a1 += sp[1] * w; a2 += sp[2] * w; a3 += sp[3] * w; a4 += sp[4] * w;
    }
    float* op = agg1 + (size_t)i * NF0;
    op[0] = a0; op[1] = a1; op[2] = a2; op[3] = a3; op[4] = a4;
}

// ---------------- fused per-node transform: g = relu(agg1@W1 + b1) @ W2c ----------------

__global__ __launch_bounds__(256) void k_node(const float* __restrict__ agg1,
                                              const float* __restrict__ W1,
                                              const float* __restrict__ b1,
                                              const float* __restrict__ W2c,
                                              float* __restrict__ g, int N) {
    __shared__ float t_lds[32][F1 + 4];
    int tid = threadIdx.x;
    int nb = blockIdx.x * 32;

    // Phase 1: t = relu(agg1 @ W1 + b1) for 32 nodes, 8 threads per node
    {
        int nl = tid >> 3;
        int ko = tid & 7;
        int node = nb + nl;
        float a0 = 0.f, a1 = 0.f, a2 = 0.f, a3 = 0.f, a4 = 0.f;
        if (node < N) {
            const float* ap = agg1 + (size_t)node * NF0;
            a0 = ap[0]; a1 = ap[1]; a2 = ap[2]; a3 = ap[3]; a4 = ap[4];
        }
        #pragma unroll
        for (int kk = 0; kk < 40; ++kk) {
            int k = ko + (kk << 3);
            float v = b1[k];
            v += a0 * W1[k];
            v += a1 * W1[F1 + k];
            v += a2 * W1[2 * F1 + k];
            v += a3 * W1[3 * F1 + k];
            v += a4 * W1[4 * F1 + k];
            t_lds[nl][k] = fmaxf(v, 0.f);
        }
    }
    __syncthreads();

    // Phase 2: g = t @ W2c
    int wv = tid >> 6;
    int lane = tid & 63;
    float acc0[8] = {0.f, 0.f, 0.f, 0.f, 0.f, 0.f, 0.f, 0.f};
    float acc1[8] = {0.f, 0.f, 0.f, 0.f, 0.f, 0.f, 0.f, 0.f};
    const float* wp0 = W2c + lane;
    const float* wp1 = W2c + 64 + (lane < 16 ? lane : 0);
    int row0 = wv * 8;

    for (int k = 0; k < F1; k += 4) {
        float wa0 = wp0[(k + 0) * F3];
        float wa1 = wp0[(k + 1) * F3];
        float wa2 = wp0[(k + 2) * F3];
        float wa3 = wp0[(k + 3) * F3];
        float wb0 = wp1[(k + 0) * F3];
        float wb1 = wp1[(k + 1) * F3];
        float wb2 = wp1[(k + 2) * F3];
        float wb3 = wp1[(k + 3) * F3];
        #pragma unroll
        for (int nn = 0; nn < 8; ++nn) {
            const float4 t4 = *(const float4*)&t_lds[row0 + nn][k];
            acc0[nn] += t4.x * wa0 + t4.y * wa1 + t4.z * wa2 + t4.w * wa3;
            acc1[nn] += t4.x * wb0 + t4.y * wb1 + t4.z * wb2 + t4.w * wb3;
        }
    }

    int nodebase = nb + row0;
    #pragma unroll
    for (int nn = 0; nn < 8; ++nn) {
        int node = nodebase + nn;
        if (node < N) {
            g[(size_t)node * F3 + lane] = acc0[nn];
            if (lane < 16) g[(size_t)node * F3 + 64 + lane] = acc1[nn];
        }
    }
}

// ---------------- conv2 aggregation via CSR gather -> d_out (self + bias folded) ----------------

__global__ void k_aggB(const float* __restrict__ g, const float* __restrict__ dinv,
                       const float* __restrict__ bc, const int* __restrict__ rowoff,
                       const int* __restrict__ csr_src, const float* __restrict__ csr_w,
                       float* __restrict__ out, int N) {
    int gid = blockIdx.x * blockDim.x + threadIdx.x;
    if (gid >= N * C4) return;
    int i = gid / C4, c = gid % C4;
    float di = dinv[i];
    float sc = di * di;
    const float4* g4 = (const float4*)g;
    float4 acc = g4[(size_t)i * C4 + c];
    float4 b4 = ((const float4*)bc)[c];
    acc.x = acc.x * sc + b4.x;
    acc.y = acc.y * sc + b4.y;
    acc.z = acc.z * sc + b4.z;
    acc.w = acc.w * sc + b4.w;
    int b = rowoff[i], en = rowoff[i + 1];
    for (int j = b; j < en; ++j) {
        int s = csr_src[j];
        float w = csr_w[j];
        float4 v = g4[(size_t)s * C4 + c];
        acc.x += v.x * w;
        acc.y += v.y * w;
        acc.z += v.z * w;
        acc.w += v.w * w;
    }
    ((float4*)out)[gid] = acc;
}

// ---------------- launch ----------------

static inline size_t align256(size_t x) { return (x + 255) & ~(size_t)255; }

extern "C" void kernel_launch(void* const* d_in, const int* in_sizes, int n_in,
                              void* d_out, int out_size, void* d_ws, size_t ws_size,
                              hipStream_t stream) {
    const float* x  = (const float*)d_in[0];
    const void*  ei = d_in[1];
    const float* ew = (const float*)d_in[2];
    const float* W1 = (const float*)d_in[3];
    const float* b1 = (const float*)d_in[4];
    const float* W2 = (const float*)d_in[5];
    const float* b2 = (const float*)d_in[6];
    const float* We = (const float*)d_in[7];
    const float* be = (const float*)d_in[8];
    float* out = (float*)d_out;

    int N = in_sizes[0] / NF0;
    int E = in_sizes[2];

    char* p = (char*)d_ws;
    auto alloc = [&](size_t bytes) { char* r = p; p += align256(bytes); return r; };
    int*   flag    = (int*)  alloc(4);
    int*   srcv    = (int*)  alloc((size_t)E * 4);
    int*   dstv    = (int*)  alloc((size_t)E * 4);
    float* dinv    = (float*)alloc((size_t)N * 4);
    int*   cnt     = (int*)  alloc((size_t)N * 4);
    int*   bsum    = (int*)  alloc(2048);
    int*   rowoff  = (int*)  alloc((size_t)(N + 1) * 4);
    int*   cursor  = (int*)  alloc((size_t)N * 4);
    int*   csr_src = (int*)  alloc((size_t)E * 4);
    float* csr_w   = (float*)alloc((size_t)E * 4);
    float* agg1    = (float*)alloc((size_t)N * NF0 * 4);
    float* W2c     = (float*)alloc((size_t)F1 * F3 * 4);
    float* bc      = (float*)alloc((size_t)F3 * 4);
    float* g       = (float*)alloc((size_t)N * F3 * 4);

    int eb = (E + 255) / 256;
    int nb1 = (N + 255) / 256;   // 391 for N=100000, fits single-block scanB (<=512)
    int npairs = E < 2048 ? E : 2048;

    k_detect<<<1, 256, 0, stream>>>((const unsigned int*)ei, npairs, flag);
    k_convert<<<eb, 256, 0, stream>>>(ei, E, flag, srcv, dstv);

    hipMemsetAsync(dinv, 0, (size_t)N * 4, stream);
    hipMemsetAsync(cnt, 0, (size_t)N * 4, stream);
    k_hist<<<eb, 256, 0, stream>>>(dstv, ew, dinv, cnt, E);
    k_dinv<<<nb1, 256, 0, stream>>>(dinv, N);

    k_scanA<<<nb1, 256, 0, stream>>>(cnt, bsum, N);
    k_scanB<<<1, 512, 0, stream>>>(bsum, nb1, rowoff, N, E);
    k_scanC<<<nb1, 256, 0, stream>>>(cnt, bsum, rowoff, cursor, N);
    k_scatter<<<eb, 256, 0, stream>>>(srcv, dstv, ew, dinv, cursor, csr_src, csr_w, E);

    k_w2c<<<(F1 * F3 + 255) / 256, 256, 0, stream>>>(W2, We, W2c);
    k_bc<<<1, 128, 0, stream>>>(b2, We, be, bc);

    k_aggA<<<nb1, 256, 0, stream>>>(x, dinv, rowoff, csr_src, csr_w, agg1, N);
    k_node<<<(N + 31) / 32, 256, 0, stream>>>(agg1, W1, b1, W2c, g, N);
    k_aggB<<<(N * C4 + 255) / 256, 256, 0, stream>>>(g, dinv, bc, rowoff, csr_src, csr_w, out, N);
}

// Round 3
// 281.415 us; speedup vs baseline: 4.6304x; 1.4257x over previous
//
#include <hip/hip_runtime.h>

#define NF0 5
#define F1 320
#define F2 160
#define F3 80

typedef float f32x4 __attribute__((ext_vector_type(4)));
typedef short bf16x8 __attribute__((ext_vector_type(8)));

__device__ __forceinline__ unsigned short f2bf_rne(float x) {
    unsigned int u = __builtin_bit_cast(unsigned int, x);
    unsigned int r = (u + 0x7fffu + ((u >> 16) & 1u)) >> 16;
    return (unsigned short)r;
}

// ---------------- edge-index width detection + conversion ----------------

__global__ void k_detect(const unsigned int* ei32, int npairs, int* flag) {
    __shared__ int ok;
    if (threadIdx.x == 0) ok = 1;
    __syncthreads();
    for (int i = threadIdx.x; i < npairs; i += blockDim.x) {
        if (ei32[2 * i + 1] != 0u) ok = 0;
    }
    __syncthreads();
    if (threadIdx.x == 0) *flag = ok;        // 1 => int64 storage, 0 => int32
}

__global__ void k_convert(const void* ei, int E, const int* flag, int* srcv, int* dstv) {
    int e = blockIdx.x * blockDim.x + threadIdx.x;
    if (e >= E) return;
    if (*flag) {
        const long long* p = (const long long*)ei;
        srcv[e] = (int)p[e];
        dstv[e] = (int)p[E + e];
    } else {
        const int* p = (const int*)ei;
        srcv[e] = p[e];
        dstv[e] = p[E + e];
    }
}

// ---------------- degree (float) + in-degree count (int) ----------------

__global__ void k_hist(const int* __restrict__ dstv, const float* __restrict__ ew,
                       float* __restrict__ deg, int* __restrict__ cnt, int E) {
    int e = blockIdx.x * blockDim.x + threadIdx.x;
    if (e >= E) return;
    int d = dstv[e];
    atomicAdd(&deg[d], ew[e]);
    atomicAdd(&cnt[d], 1);
}

__global__ void k_dinv(float* deg, int N) {
    int i = blockIdx.x * blockDim.x + threadIdx.x;
    if (i < N) {
        float d = deg[i] + 1.0f;
        deg[i] = rsqrtf(d);
    }
}

// ---------------- exclusive scan of cnt -> rowoff ----------------

__global__ void k_scanA(const int* __restrict__ cnt, int* __restrict__ bsum, int N) {
    __shared__ int s[256];
    int t = threadIdx.x;
    int gid = blockIdx.x * 256 + t;
    s[t] = gid < N ? cnt[gid] : 0;
    __syncthreads();
    for (int o = 128; o > 0; o >>= 1) {
        if (t < o) s[t] += s[t + o];
        __syncthreads();
    }
    if (t == 0) bsum[blockIdx.x] = s[0];
}

__global__ void k_scanB(int* bsum, int nb, int* rowoff, int N, int E) {
    __shared__ int s[512];
    int t = threadIdx.x;
    int v = t < nb ? bsum[t] : 0;
    s[t] = v;
    __syncthreads();
    for (int o = 1; o < 512; o <<= 1) {
        int a = (t >= o) ? s[t - o] : 0;
        __syncthreads();
        s[t] += a;
        __syncthreads();
    }
    if (t < nb) bsum[t] = s[t] - v;
    if (t == 0) rowoff[N] = E;
}

__global__ void k_scanC(const int* __restrict__ cnt, const int* __restrict__ bsum_ex,
                        int* __restrict__ rowoff, int* __restrict__ cursor, int N) {
    __shared__ int s[256];
    int t = threadIdx.x;
    int gid = blockIdx.x * 256 + t;
    int v = gid < N ? cnt[gid] : 0;
    s[t] = v;
    __syncthreads();
    for (int o = 1; o < 256; o <<= 1) {
        int a = (t >= o) ? s[t - o] : 0;
        __syncthreads();
        s[t] += a;
        __syncthreads();
    }
    if (gid < N) {
        int ex = bsum_ex[blockIdx.x] + s[t] - v;
        rowoff[gid] = ex;
        cursor[gid] = ex;
    }
}

// ---------------- scatter edges into CSR (by dst), fold norm ----------------

__global__ void k_scatter(const int* __restrict__ srcv, const int* __restrict__ dstv,
                          const float* __restrict__ ew, const float* __restrict__ dinv,
                          int* __restrict__ cursor, int* __restrict__ csr_src,
                          float* __restrict__ csr_w, int E) {
    int e = blockIdx.x * blockDim.x + threadIdx.x;
    if (e >= E) return;
    int s = srcv[e], d = dstv[e];
    int pos = atomicAdd(&cursor[d], 1);
    csr_src[pos] = s;
    csr_w[pos] = dinv[s] * ew[e] * dinv[d];
}

// ---------------- folded weights: W2c = W2 @ We, bc = b2 @ We + be ----------------

__global__ void k_w2c(const float* __restrict__ W2, const float* __restrict__ We,
                      float* __restrict__ W2c) {
    int o = blockIdx.x * blockDim.x + threadIdx.x;
    if (o >= F1 * F3) return;
    int k = o / F3, j = o % F3;
    float s = 0.f;
    for (int m = 0; m < F2; ++m) s += W2[k * F2 + m] * We[m * F3 + j];
    W2c[o] = s;
}

__global__ void k_bc(const float* b2, const float* We, const float* be, float* bc) {
    int j = threadIdx.x;
    if (j >= F3) return;
    float s = be[j];
    for (int k = 0; k < F2; ++k) s += b2[k] * We[k * F3 + j];
    bc[j] = s;
}

// ---------------- W2c -> MFMA B-fragments, split bf16 hi/lo ----------------
// Fragment (kk, ct): lane l holds B[32*kk + 8*(l>>4) + i][16*ct + (l&15)], i=0..7.
// Stored at ushort index ((kk*5+ct)*64 + l)*8 + i.

__global__ void k_wfrag(const float* __restrict__ W2c, unsigned short* __restrict__ Bhi,
                        unsigned short* __restrict__ Blo) {
    int t = blockIdx.x * blockDim.x + threadIdx.x;
    if (t >= 50 * 64) return;
    int fid = t >> 6, lane = t & 63;
    int kk = fid / 5, ct = fid % 5;
    int col = ct * 16 + (lane & 15);
    int row0 = kk * 32 + (lane >> 4) * 8;
    size_t ob = (size_t)t * 8;
    #pragma unroll
    for (int i = 0; i < 8; ++i) {
        float v = W2c[(size_t)(row0 + i) * F3 + col];
        unsigned int ub = __builtin_bit_cast(unsigned int, v);
        float hf = __builtin_bit_cast(float, ub & 0xffff0000u);
        Bhi[ob + i] = (unsigned short)(ub >> 16);      // truncated hi
        Blo[ob + i] = f2bf_rne(v - hf);                // residual
    }
}

// ---------------- conv1 aggregation via CSR gather (5 features, self folded) ----------------

__global__ void k_aggA(const float* __restrict__ x, const float* __restrict__ dinv,
                       const int* __restrict__ rowoff, const int* __restrict__ csr_src,
                       const float* __restrict__ csr_w, float* __restrict__ agg1, int N) {
    int i = blockIdx.x * blockDim.x + threadIdx.x;
    if (i >= N) return;
    float di = dinv[i];
    float sc = di * di;
    const float* xp = x + (size_t)i * NF0;
    float a0 = xp[0] * sc, a1 = xp[1] * sc, a2 = xp[2] * sc, a3 = xp[3] * sc, a4 = xp[4] * sc;
    int b = rowoff[i], en = rowoff[i + 1];
    for (int j = b; j < en; ++j) {
        int s = csr_src[j];
        float w = csr_w[j];
        const float* sp = x + (size_t)s * NF0;
        a0 += sp[0] * w; a1 += sp[1] * w; a2 += sp[2] * w; a3 += sp[3] * w; a4 += sp[4] * w;
    }
    float* op = agg1 + (size_t)i * NF0;
    op[0] = a0; op[1] = a1; op[2] = a2; op[3] = a3; op[4] = a4;
}

// ---------------- fused node transform via MFMA ----------------
// Block = 256 threads = 4 waves, 64 nodes (wave w: nodes blk*64 + w*16 + 0..15).
// Phase 1 (VALU): each thread computes t = relu(agg1@W1+b1) exactly at its own
// A-fragment positions: node = base + (l&15), k = 32*kk + 8*(l>>4) + i.
// Phase 2 (MFMA): 3-product split-bf16, B-fragments streamed from global (L2-hot).
// D layout (verified m89): col = lane&15, row = (lane>>4)*4 + reg.

__global__ __launch_bounds__(256) void k_node(const float* __restrict__ agg1,
                                              const float* __restrict__ W1,
                                              const float* __restrict__ b1,
                                              const unsigned short* __restrict__ Bhi,
                                              const unsigned short* __restrict__ Blo,
                                              float* __restrict__ g, int N) {
    int tid = threadIdx.x;
    int w = tid >> 6, l = tid & 63;
    int nl = l & 15, kg = l >> 4;
    int nb = blockIdx.x * 64 + w * 16;
    int node = nb + nl;

    float a0 = 0.f, a1 = 0.f, a2 = 0.f, a3 = 0.f, a4 = 0.f;
    if (node < N) {
        const float* ap = agg1 + (size_t)node * NF0;
        a0 = ap[0]; a1 = ap[1]; a2 = ap[2]; a3 = ap[3]; a4 = ap[4];
    }

    bf16x8 ahi[10], alo[10];
    #pragma unroll
    for (int kk = 0; kk < 10; ++kk) {
        int k0 = kk * 32 + kg * 8;
        float v[8];
        {
            const float4* bp = (const float4*)(b1 + k0);
            float4 v0 = bp[0], v1 = bp[1];
            v[0] = v0.x; v[1] = v0.y; v[2] = v0.z; v[3] = v0.w;
            v[4] = v1.x; v[5] = v1.y; v[6] = v1.z; v[7] = v1.w;
        }
        #pragma unroll
        for (int j = 0; j < 5; ++j) {
            float aj = (j == 0) ? a0 : (j == 1) ? a1 : (j == 2) ? a2 : (j == 3) ? a3 : a4;
            const float4* wp = (const float4*)(W1 + j * F1 + k0);
            float4 w0 = wp[0], w1 = wp[1];
            v[0] += aj * w0.x; v[1] += aj * w0.y; v[2] += aj * w0.z; v[3] += aj * w0.w;
            v[4] += aj * w1.x; v[5] += aj * w1.y; v[6] += aj * w1.z; v[7] += aj * w1.w;
        }
        #pragma unroll
        for (int i = 0; i < 8; ++i) {
            float t = fmaxf(v[i], 0.f);
            unsigned int ub = __builtin_bit_cast(unsigned int, t);
            float hf = __builtin_bit_cast(float, ub & 0xffff0000u);
            ahi[kk][i] = (short)(ub >> 16);
            alo[kk][i] = (short)f2bf_rne(t - hf);
        }
    }

    f32x4 zero = {0.f, 0.f, 0.f, 0.f};
    f32x4 acc[5] = {zero, zero, zero, zero, zero};
    const bf16x8* bhp = (const bf16x8*)Bhi;
    const bf16x8* blp = (const bf16x8*)Blo;
    #pragma unroll
    for (int kk = 0; kk < 10; ++kk) {
        #pragma unroll
        for (int ct = 0; ct < 5; ++ct) {
            int idx = (kk * 5 + ct) * 64 + l;
            bf16x8 bh = bhp[idx];
            bf16x8 bl = blp[idx];
            acc[ct] = __builtin_amdgcn_mfma_f32_16x16x32_bf16(ahi[kk], bh, acc[ct], 0, 0, 0);
            acc[ct] = __builtin_amdgcn_mfma_f32_16x16x32_bf16(ahi[kk], bl, acc[ct], 0, 0, 0);
            acc[ct] = __builtin_amdgcn_mfma_f32_16x16x32_bf16(alo[kk], bh, acc[ct], 0, 0, 0);
        }
    }

    #pragma unroll
    for (int ct = 0; ct < 5; ++ct) {
        #pragma unroll
        for (int r = 0; r < 4; ++r) {
            int nrow = nb + kg * 4 + r;
            if (nrow < N) g[(size_t)nrow * F3 + ct * 16 + nl] = acc[ct][r];
        }
    }
}

// ---------------- conv2 aggregation via CSR gather -> d_out ----------------
// 5 threads per node; thread c owns contiguous chunks 4c..4c+3 (64 B slice).

__global__ void k_aggB(const float* __restrict__ g, const float* __restrict__ dinv,
                       const float* __restrict__ bc, const int* __restrict__ rowoff,
                       const int* __restrict__ csr_src, const float* __restrict__ csr_w,
                       float* __restrict__ out, int N) {
    int t = blockIdx.x * blockDim.x + threadIdx.x;
    if (t >= N * 5) return;
    int i = t / 5, c = (t % 5) * 4;
    float di = dinv[i];
    float sc = di * di;
    const float4* g4 = (const float4*)g;
    const float4* b4 = (const float4*)bc;
    float4 acc0, acc1, acc2, acc3;
    {
        const float4* sp = g4 + (size_t)i * 20 + c;
        float4 s0 = sp[0], s1 = sp[1], s2 = sp[2], s3 = sp[3];
        float4 q0 = b4[c], q1 = b4[c + 1], q2 = b4[c + 2], q3 = b4[c + 3];
        acc0.x = s0.x * sc + q0.x; acc0.y = s0.y * sc + q0.y; acc0.z = s0.z * sc + q0.z; acc0.w = s0.w * sc + q0.w;
        acc1.x = s1.x * sc + q1.x; acc1.y = s1.y * sc + q1.y; acc1.z = s1.z * sc + q1.z; acc1.w = s1.w * sc + q1.w;
        acc2.x = s2.x * sc + q2.x; acc2.y = s2.y * sc + q2.y; acc2.z = s2.z * sc + q2.z; acc2.w = s2.w * sc + q2.w;
        acc3.x = s3.x * sc + q3.x; acc3.y = s3.y * sc + q3.y; acc3.z = s3.z * sc + q3.z; acc3.w = s3.w * sc + q3.w;
    }
    int b = rowoff[i], en = rowoff[i + 1];
    for (int j = b; j < en; ++j) {
        int s = csr_src[j];
        float wt = csr_w[j];
        const float4* sp = g4 + (size_t)s * 20 + c;
        float4 s0 = sp[0], s1 = sp[1], s2 = sp[2], s3 = sp[3];
        acc0.x += s0.x * wt; acc0.y += s0.y * wt; acc0.z += s0.z * wt; acc0.w += s0.w * wt;
        acc1.x += s1.x * wt; acc1.y += s1.y * wt; acc1.z += s1.z * wt; acc1.w += s1.w * wt;
        acc2.x += s2.x * wt; acc2.y += s2.y * wt; acc2.z += s2.z * wt; acc2.w += s2.w * wt;
        acc3.x += s3.x * wt; acc3.y += s3.y * wt; acc3.z += s3.z * wt; acc3.w += s3.w * wt;
    }
    float4* op = (float4*)out + (size_t)i * 20 + c;
    op[0] = acc0; op[1] = acc1; op[2] = acc2; op[3] = acc3;
}

// ---------------- launch ----------------

static inline size_t align256(size_t x) { return (x + 255) & ~(size_t)255; }

extern "C" void kernel_launch(void* const* d_in, const int* in_sizes, int n_in,
                              void* d_out, int out_size, void* d_ws, size_t ws_size,
                              hipStream_t stream) {
    const float* x  = (const float*)d_in[0];
    const void*  ei = d_in[1];
    const float* ew = (const float*)d_in[2];
    const float* W1 = (const float*)d_in[3];
    const float* b1 = (const float*)d_in[4];
    const float* W2 = (const float*)d_in[5];
    const float* b2 = (const float*)d_in[6];
    const float* We = (const float*)d_in[7];
    const float* be = (const float*)d_in[8];
    float* out = (float*)d_out;

    int N = in_sizes[0] / NF0;
    int E = in_sizes[2];

    char* p = (char*)d_ws;
    auto alloc = [&](size_t bytes) { char* r = p; p += align256(bytes); return r; };
    int*   flag    = (int*)  alloc(4);
    int*   srcv    = (int*)  alloc((size_t)E * 4);
    int*   dstv    = (int*)  alloc((size_t)E * 4);
    float* dinv    = (float*)alloc((size_t)N * 4);
    int*   cnt     = (int*)  alloc((size_t)N * 4);
    int*   bsum    = (int*)  alloc(2048);
    int*   rowoff  = (int*)  alloc((size_t)(N + 1) * 4);
    int*   cursor  = (int*)  alloc((size_t)N * 4);
    int*   csr_src = (int*)  alloc((size_t)E * 4);
    float* csr_w   = (float*)alloc((size_t)E * 4);
    float* agg1    = (float*)alloc((size_t)N * NF0 * 4);
    float* W2c     = (float*)alloc((size_t)F1 * F3 * 4);
    float* bc      = (float*)alloc((size_t)F3 * 4);
    unsigned short* Bhi = (unsigned short*)alloc((size_t)50 * 64 * 8 * 2);
    unsigned short* Blo = (unsigned short*)alloc((size_t)50 * 64 * 8 * 2);
    float* g       = (float*)alloc((size_t)N * F3 * 4);

    int eb = (E + 255) / 256;
    int nb1 = (N + 255) / 256;   // 391 for N=100000, fits single-block scanB (<=512)
    int npairs = E < 2048 ? E : 2048;

    k_detect<<<1, 256, 0, stream>>>((const unsigned int*)ei, npairs, flag);
    k_convert<<<eb, 256, 0, stream>>>(ei, E, flag, srcv, dstv);

    hipMemsetAsync(dinv, 0, (size_t)N * 4, stream);
    hipMemsetAsync(cnt, 0, (size_t)N * 4, stream);
    k_hist<<<eb, 256, 0, stream>>>(dstv, ew, dinv, cnt, E);
    k_dinv<<<nb1, 256, 0, stream>>>(dinv, N);

    k_scanA<<<nb1, 256, 0, stream>>>(cnt, bsum, N);
    k_scanB<<<1, 512, 0, stream>>>(bsum, nb1, rowoff, N, E);
    k_scanC<<<nb1, 256, 0, stream>>>(cnt, bsum, rowoff, cursor, N);
    k_scatter<<<eb, 256, 0, stream>>>(srcv, dstv, ew, dinv, cursor, csr_src, csr_w, E);

    k_w2c<<<(F1 * F3 + 255) / 256, 256, 0, stream>>>(W2, We, W2c);
    k_bc<<<1, 128, 0, stream>>>(b2, We, be, bc);
    k_wfrag<<<(50 * 64 + 255) / 256, 256, 0, stream>>>(W2c, Bhi, Blo);

    k_aggA<<<nb1, 256, 0, stream>>>(x, dinv, rowoff, csr_src, csr_w, agg1, N);
    k_node<<<(N + 63) / 64, 256, 0, stream>>>(agg1, W1, b1, Bhi, Blo, g, N);
    k_aggB<<<(N * 5 + 255) / 256, 256, 0, stream>>>(g, dinv, bc, rowoff, csr_src, csr_w, out, N);
}

// Round 4
// 246.421 us; speedup vs baseline: 5.2879x; 1.1420x over previous
//
#include <hip/hip_runtime.h>

#define NF0 5
#define F1 320
#define F2 160
#define F3 80

typedef float f32x4 __attribute__((ext_vector_type(4)));
typedef short bf16x8 __attribute__((ext_vector_type(8)));

__device__ __forceinline__ unsigned short f2bf_rne(float x) {
    unsigned int u = __builtin_bit_cast(unsigned int, x);
    unsigned int r = (u + 0x7fffu + ((u >> 16) & 1u)) >> 16;
    return (unsigned short)r;
}

// ---------------- edge-index width detection ----------------

__global__ void k_detect(const unsigned int* ei32, int npairs, int* flag) {
    __shared__ int ok;
    if (threadIdx.x == 0) ok = 1;
    __syncthreads();
    for (int i = threadIdx.x; i < npairs; i += blockDim.x) {
        if (ei32[2 * i + 1] != 0u) ok = 0;   // benign race: everyone writes 0
    }
    __syncthreads();
    if (threadIdx.x == 0) *flag = ok;        // 1 => int64 storage, 0 => int32
}

// ---------------- bucket scatter: 1 atomic/edge ----------------
// bucket[d*cap + pos] = {src, ew}; overflow (pos >= cap) goes to ovf list.

__global__ void k_bucket(const void* ei, const float* __restrict__ ew, const int* __restrict__ flag,
                         int* __restrict__ cnt, int2* __restrict__ bucket, int cap,
                         int* __restrict__ ovf_n, int* __restrict__ ovf, int ovf_cap, int E) {
    int e = blockIdx.x * blockDim.x + threadIdx.x;
    if (e >= E) return;
    int s, d;
    if (*flag) {
        const long long* p = (const long long*)ei;
        s = (int)p[e]; d = (int)p[E + e];
    } else {
        const int* p = (const int*)ei;
        s = p[e]; d = p[E + e];
    }
    float w = ew[e];
    int pos = atomicAdd(&cnt[d], 1);
    if (pos < cap) {
        int2 pk;
        pk.x = s;
        pk.y = __float_as_int(w);
        bucket[(size_t)d * cap + pos] = pk;
    } else {
        int o = atomicAdd(ovf_n, 1);
        if (o < ovf_cap) {
            ovf[3 * o] = s;
            ovf[3 * o + 1] = d;
            ovf[3 * o + 2] = __float_as_int(w);
        }
    }
}

// overflow edges' ew into deg (deg pre-zeroed)
__global__ void k_fixdeg(const int* __restrict__ ovf_n, const int* __restrict__ ovf, int ovf_cap,
                         float* __restrict__ deg) {
    int n = *ovf_n; if (n > ovf_cap) n = ovf_cap;
    for (int j = blockIdx.x * blockDim.x + threadIdx.x; j < n; j += gridDim.x * blockDim.x)
        atomicAdd(&deg[ovf[3 * j + 1]], __int_as_float(ovf[3 * j + 2]));
}

// deg[i] = (ovf part) + 1 + sum(bucket ew)  ->  dinv in place
__global__ void k_deg(const int* __restrict__ cnt, const int2* __restrict__ bucket, int cap,
                      float* __restrict__ deg, int N) {
    int i = blockIdx.x * blockDim.x + threadIdx.x;
    if (i >= N) return;
    float s = deg[i] + 1.0f;
    int c = cnt[i]; if (c > cap) c = cap;
    const int2* row = bucket + (size_t)i * cap;
    for (int j = 0; j < c; ++j) s += __int_as_float(row[j].y);
    deg[i] = rsqrtf(s);
}

// ---------------- bc = b2 @ We + be ----------------

__global__ void k_bc(const float* b2, const float* We, const float* be, float* bc) {
    int j = threadIdx.x;
    if (j >= F3) return;
    float s = be[j];
    for (int k = 0; k < F2; ++k) s += b2[k] * We[k * F3 + j];
    bc[j] = s;
}

// ---------------- (W2@We) -> MFMA B-fragments, split bf16 hi/lo, direct ----------------
// Fragment (kk, ct): lane l holds B[32*kk + 8*(l>>4) + i][16*ct + (l&15)], i=0..7.

__global__ void k_wfrag(const float* __restrict__ W2, const float* __restrict__ We,
                        unsigned short* __restrict__ Bhi, unsigned short* __restrict__ Blo) {
    int t = blockIdx.x * blockDim.x + threadIdx.x;
    if (t >= 50 * 64) return;
    int fid = t >> 6, lane = t & 63;
    int kk = fid / 5, ct = fid % 5;
    int col = ct * 16 + (lane & 15);
    int row0 = kk * 32 + (lane >> 4) * 8;
    float acc[8] = {0.f, 0.f, 0.f, 0.f, 0.f, 0.f, 0.f, 0.f};
    for (int m = 0; m < F2; ++m) {
        float wv = We[m * F3 + col];
        #pragma unroll
        for (int i = 0; i < 8; ++i)
            acc[i] += W2[(size_t)(row0 + i) * F2 + m] * wv;
    }
    size_t ob = (size_t)t * 8;
    #pragma unroll
    for (int i = 0; i < 8; ++i) {
        float v = acc[i];
        unsigned int ub = __builtin_bit_cast(unsigned int, v);
        float hf = __builtin_bit_cast(float, ub & 0xffff0000u);
        Bhi[ob + i] = (unsigned short)(ub >> 16);      // truncated hi
        Blo[ob + i] = f2bf_rne(v - hf);                // residual
    }
}

// ---------------- conv1 aggregation via bucket gather (5 features, self folded) ----------------

__global__ void k_aggA(const float* __restrict__ x, const float* __restrict__ dinv,
                       const int* __restrict__ cnt, const int2* __restrict__ bucket, int cap,
                       float* __restrict__ agg1, int N) {
    int i = blockIdx.x * blockDim.x + threadIdx.x;
    if (i >= N) return;
    float di = dinv[i];
    float sc = di * di;
    const float* xp = x + (size_t)i * NF0;
    float a0 = xp[0] * sc, a1 = xp[1] * sc, a2 = xp[2] * sc, a3 = xp[3] * sc, a4 = xp[4] * sc;
    int c = cnt[i]; if (c > cap) c = cap;
    const int2* row = bucket + (size_t)i * cap;
    for (int j = 0; j < c; ++j) {
        int2 pk = row[j];
        int s = pk.x;
        float w = di * __int_as_float(pk.y) * dinv[s];
        const float* sp = x + (size_t)s * NF0;
        a0 += sp[0] * w; a1 += sp[1] * w; a2 += sp[2] * w; a3 += sp[3] * w; a4 += sp[4] * w;
    }
    float* op = agg1 + (size_t)i * NF0;
    op[0] = a0; op[1] = a1; op[2] = a2; op[3] = a3; op[4] = a4;
}

__global__ void k_fixA(const float* __restrict__ x, const float* __restrict__ dinv,
                       const int* __restrict__ ovf_n, const int* __restrict__ ovf, int ovf_cap,
                       float* __restrict__ agg1) {
    int n = *ovf_n; if (n > ovf_cap) n = ovf_cap;
    for (int j = blockIdx.x * blockDim.x + threadIdx.x; j < n; j += gridDim.x * blockDim.x) {
        int s = ovf[3 * j], d = ovf[3 * j + 1];
        float w = dinv[s] * __int_as_float(ovf[3 * j + 2]) * dinv[d];
        #pragma unroll
        for (int f = 0; f < NF0; ++f)
            atomicAdd(&agg1[(size_t)d * NF0 + f], x[(size_t)s * NF0 + f] * w);
    }
}

// ---------------- fused node transform via MFMA (split-bf16, 3 products) ----------------
// Block = 256 threads = 4 waves, 64 nodes. Phase 1 (VALU): t = relu(agg1@W1+b1)
// computed directly at each lane's A-fragment positions. Phase 2: MFMA with
// B-fragments streamed from global (L2-hot). D layout: col=lane&15, row=(lane>>4)*4+reg.

__global__ __launch_bounds__(256) void k_node(const float* __restrict__ agg1,
                                              const float* __restrict__ W1,
                                              const float* __restrict__ b1,
                                              const unsigned short* __restrict__ Bhi,
                                              const unsigned short* __restrict__ Blo,
                                              float* __restrict__ g, int N) {
    int tid = threadIdx.x;
    int w = tid >> 6, l = tid & 63;
    int nl = l & 15, kg = l >> 4;
    int nb = blockIdx.x * 64 + w * 16;
    int node = nb + nl;

    float a0 = 0.f, a1 = 0.f, a2 = 0.f, a3 = 0.f, a4 = 0.f;
    if (node < N) {
        const float* ap = agg1 + (size_t)node * NF0;
        a0 = ap[0]; a1 = ap[1]; a2 = ap[2]; a3 = ap[3]; a4 = ap[4];
    }

    bf16x8 ahi[10], alo[10];
    #pragma unroll
    for (int kk = 0; kk < 10; ++kk) {
        int k0 = kk * 32 + kg * 8;
        float v[8];
        {
            const float4* bp = (const float4*)(b1 + k0);
            float4 v0 = bp[0], v1 = bp[1];
            v[0] = v0.x; v[1] = v0.y; v[2] = v0.z; v[3] = v0.w;
            v[4] = v1.x; v[5] = v1.y; v[6] = v1.z; v[7] = v1.w;
        }
        #pragma unroll
        for (int j = 0; j < 5; ++j) {
            float aj = (j == 0) ? a0 : (j == 1) ? a1 : (j == 2) ? a2 : (j == 3) ? a3 : a4;
            const float4* wp = (const float4*)(W1 + j * F1 + k0);
            float4 w0 = wp[0], w1 = wp[1];
            v[0] += aj * w0.x; v[1] += aj * w0.y; v[2] += aj * w0.z; v[3] += aj * w0.w;
            v[4] += aj * w1.x; v[5] += aj * w1.y; v[6] += aj * w1.z; v[7] += aj * w1.w;
        }
        #pragma unroll
        for (int i = 0; i < 8; ++i) {
            float t = fmaxf(v[i], 0.f);
            unsigned int ub = __builtin_bit_cast(unsigned int, t);
            float hf = __builtin_bit_cast(float, ub & 0xffff0000u);
            ahi[kk][i] = (short)(ub >> 16);
            alo[kk][i] = (short)f2bf_rne(t - hf);
        }
    }

    f32x4 zero = {0.f, 0.f, 0.f, 0.f};
    f32x4 acc[5] = {zero, zero, zero, zero, zero};
    const bf16x8* bhp = (const bf16x8*)Bhi;
    const bf16x8* blp = (const bf16x8*)Blo;
    #pragma unroll
    for (int kk = 0; kk < 10; ++kk) {
        #pragma unroll
        for (int ct = 0; ct < 5; ++ct) {
            int idx = (kk * 5 + ct) * 64 + l;
            bf16x8 bh = bhp[idx];
            bf16x8 bl = blp[idx];
            acc[ct] = __builtin_amdgcn_mfma_f32_16x16x32_bf16(ahi[kk], bh, acc[ct], 0, 0, 0);
            acc[ct] = __builtin_amdgcn_mfma_f32_16x16x32_bf16(ahi[kk], bl, acc[ct], 0, 0, 0);
            acc[ct] = __builtin_amdgcn_mfma_f32_16x16x32_bf16(alo[kk], bh, acc[ct], 0, 0, 0);
        }
    }

    #pragma unroll
    for (int ct = 0; ct < 5; ++ct) {
        #pragma unroll
        for (int r = 0; r < 4; ++r) {
            int nrow = nb + kg * 4 + r;
            if (nrow < N) g[(size_t)nrow * F3 + ct * 16 + nl] = acc[ct][r];
        }
    }
}

// ---------------- conv2 aggregation via bucket gather -> d_out ----------------
// 4 threads/node; thread c owns 5 consecutive float4 chunks (80 B slice).

__global__ void k_aggB(const float* __restrict__ g, const float* __restrict__ dinv,
                       const float* __restrict__ bc, const int* __restrict__ cnt,
                       const int2* __restrict__ bucket, int cap,
                       float* __restrict__ out, int N) {
    int t = blockIdx.x * blockDim.x + threadIdx.x;
    if (t >= N * 4) return;
    int i = t >> 2, c = (t & 3) * 5;
    float di = dinv[i];
    float sc = di * di;
    const f32x4* g4 = (const f32x4*)g;
    const f32x4* b4 = (const f32x4*)bc;
    f32x4 acc[5];
    {
        const f32x4* sp = g4 + (size_t)i * 20 + c;
        #pragma unroll
        for (int q = 0; q < 5; ++q) acc[q] = sp[q] * sc + b4[c + q];
    }
    int cn = cnt[i]; if (cn > cap) cn = cap;
    const int2* row = bucket + (size_t)i * cap;
    for (int j = 0; j < cn; ++j) {
        int2 pk = row[j];
        int s = pk.x;
        float w = di * __int_as_float(pk.y) * dinv[s];
        const f32x4* sp = g4 + (size_t)s * 20 + c;
        #pragma unroll
        for (int q = 0; q < 5; ++q) acc[q] += sp[q] * w;
    }
    f32x4* op = (f32x4*)out + (size_t)i * 20 + c;
    #pragma unroll
    for (int q = 0; q < 5; ++q) op[q] = acc[q];
}

__global__ void k_fixB(const float* __restrict__ g, const float* __restrict__ dinv,
                       const int* __restrict__ ovf_n, const int* __restrict__ ovf, int ovf_cap,
                       float* __restrict__ out) {
    int n = *ovf_n; if (n > ovf_cap) n = ovf_cap;
    for (int j = blockIdx.x * blockDim.x + threadIdx.x; j < n; j += gridDim.x * blockDim.x) {
        int s = ovf[3 * j], d = ovf[3 * j + 1];
        float w = dinv[s] * __int_as_float(ovf[3 * j + 2]) * dinv[d];
        for (int f = 0; f < F3; ++f)
            atomicAdd(&out[(size_t)d * F3 + f], g[(size_t)s * F3 + f] * w);
    }
}

// ---------------- launch ----------------

static inline size_t align256(size_t x) { return (x + 255) & ~(size_t)255; }

extern "C" void kernel_launch(void* const* d_in, const int* in_sizes, int n_in,
                              void* d_out, int out_size, void* d_ws, size_t ws_size,
                              hipStream_t stream) {
    const float* x  = (const float*)d_in[0];
    const void*  ei = d_in[1];
    const float* ew = (const float*)d_in[2];
    const float* W1 = (const float*)d_in[3];
    const float* b1 = (const float*)d_in[4];
    const float* W2 = (const float*)d_in[5];
    const float* b2 = (const float*)d_in[6];
    const float* We = (const float*)d_in[7];
    const float* be = (const float*)d_in[8];
    float* out = (float*)d_out;

    int N = in_sizes[0] / NF0;
    int E = in_sizes[2];

    const int OVF_CAP = 174000;              // 2 MB safety net; never hit at cap>=24

    char* p = (char*)d_ws;
    auto alloc = [&](size_t bytes) { char* r = p; p += align256(bytes); return r; };
    int*   flag  = (int*)alloc(4);
    int*   zreg  = (int*)alloc(((size_t)2 * N + 64) * 4);   // cnt | deg | ovf_n (one memset)
    int*   cnt   = zreg;
    float* deg   = (float*)(zreg + N);
    int*   ovf_n = zreg + 2 * N;
    int*   ovf   = (int*)  alloc((size_t)OVF_CAP * 12);
    float* agg1  = (float*)alloc((size_t)N * NF0 * 4);
    float* bc    = (float*)alloc((size_t)F3 * 4);
    unsigned short* Bhi = (unsigned short*)alloc((size_t)50 * 64 * 8 * 2);
    unsigned short* Blo = (unsigned short*)alloc((size_t)50 * 64 * 8 * 2);
    float* g     = (float*)alloc((size_t)N * F3 * 4);

    // adaptive bucket capacity (8 B per slot); CAP=32 => Poisson(8) overflow ~0
    size_t fixed = (size_t)(p - (char*)d_ws) + (1 << 20);
    int cap = 32;
    if (ws_size > fixed) {
        size_t avail = (ws_size - fixed) / ((size_t)N * 8);
        if (avail < 32) cap = (int)avail;
    } else cap = 4;
    if (cap < 4) cap = 4;
    int2* bucket = (int2*)alloc((size_t)N * cap * 8);

    int eb  = (E + 255) / 256;
    int nb1 = (N + 255) / 256;
    int npairs = E < 2048 ? E : 2048;

    hipMemsetAsync(zreg, 0, ((size_t)2 * N + 64) * 4, stream);
    k_detect<<<1, 256, 0, stream>>>((const unsigned int*)ei, npairs, flag);
    k_bucket<<<eb, 256, 0, stream>>>(ei, ew, flag, cnt, bucket, cap, ovf_n, ovf, OVF_CAP, E);
    k_fixdeg<<<16, 256, 0, stream>>>(ovf_n, ovf, OVF_CAP, deg);
    k_deg<<<nb1, 256, 0, stream>>>(cnt, bucket, cap, deg, N);

    k_bc<<<1, 128, 0, stream>>>(b2, We, be, bc);
    k_wfrag<<<(50 * 64 + 255) / 256, 256, 0, stream>>>(W2, We, Bhi, Blo);

    k_aggA<<<nb1, 256, 0, stream>>>(x, deg, cnt, bucket, cap, agg1, N);
    k_fixA<<<16, 256, 0, stream>>>(x, deg, ovf_n, ovf, OVF_CAP, agg1);
    k_node<<<(N + 63) / 64, 256, 0, stream>>>(agg1, W1, b1, Bhi, Blo, g, N);
    k_aggB<<<(N * 4 + 255) / 256, 256, 0, stream>>>(g, deg, bc, cnt, bucket, cap, out, N);
    k_fixB<<<16, 256, 0, stream>>>(g, deg, ovf_n, ovf, OVF_CAP, out);
}

// Round 5
// 212.532 us; speedup vs baseline: 6.1311x; 1.1595x over previous
//
#include <hip/hip_runtime.h>

#define NF0 5
#define F1 320
#define F2 160
#define F3 80

typedef float f32x4 __attribute__((ext_vector_type(4)));
typedef short bf16x8 __attribute__((ext_vector_type(8)));
typedef unsigned short ushortx8 __attribute__((ext_vector_type(8)));

__device__ __forceinline__ unsigned short f2bf_rne(float x) {
    unsigned int u = __builtin_bit_cast(unsigned int, x);
    unsigned int r = (u + 0x7fffu + ((u >> 16) & 1u)) >> 16;
    return (unsigned short)r;
}
__device__ __forceinline__ float bf2f(unsigned short u) {
    return __builtin_bit_cast(float, (unsigned int)u << 16);
}

// ---------------- edge-index width detection ----------------

__global__ void k_detect(const unsigned int* ei32, int npairs, int* flag) {
    __shared__ int ok;
    if (threadIdx.x == 0) ok = 1;
    __syncthreads();
    for (int i = threadIdx.x; i < npairs; i += blockDim.x) {
        if (ei32[2 * i + 1] != 0u) ok = 0;   // benign race: everyone writes 0
    }
    __syncthreads();
    if (threadIdx.x == 0) *flag = ok;        // 1 => int64 storage, 0 => int32
}

// ---------------- phase A: bin edges by dst>>8 (1 atomic/edge, clustered writes) ----------------
// bin payload: {src | (dst&255)<<24, ew}. Requires src < 2^24 (N=100000 ok).

__global__ void k_binA(const void* ei, const float* __restrict__ ew, const int* __restrict__ flag,
                       int* __restrict__ bin_cnt /*stride 16 ints*/, int2* __restrict__ bins,
                       int bin_stride, int* __restrict__ ovf_n, int* __restrict__ ovf,
                       int ovf_cap, int E) {
    int e = blockIdx.x * blockDim.x + threadIdx.x;
    if (e >= E) return;
    int s, d;
    if (*flag) {
        const long long* p = (const long long*)ei;
        s = (int)p[e]; d = (int)p[E + e];
    } else {
        const int* p = (const int*)ei;
        s = p[e]; d = p[E + e];
    }
    float w = ew[e];
    int b = d >> 8;
    int pos = atomicAdd(&bin_cnt[b * 16], 1);
    if (pos < bin_stride) {
        int2 pk;
        pk.x = s | ((d & 255) << 24);
        pk.y = __float_as_int(w);
        bins[(size_t)b * bin_stride + pos] = pk;
    } else {
        int o = atomicAdd(ovf_n, 1);
        if (o < ovf_cap) {
            ovf[3 * o] = s; ovf[3 * o + 1] = d; ovf[3 * o + 2] = __float_as_int(w);
        }
    }
}

// overflow edges' ew into deg (deg pre-zeroed); runs between binA and binB
__global__ void k_fixdeg(const int* __restrict__ ovf_n, const int* __restrict__ ovf, int ovf_cap,
                         float* __restrict__ deg) {
    int n = *ovf_n; if (n > ovf_cap) n = ovf_cap;
    for (int j = blockIdx.x * blockDim.x + threadIdx.x; j < n; j += gridDim.x * blockDim.x)
        atomicAdd(&deg[ovf[3 * j + 1]], __int_as_float(ovf[3 * j + 2]));
}

// ---------------- phase B: per-bin LDS cnt/deg, scatter to bucket, dinv in-block ----------------

__global__ __launch_bounds__(256) void k_binB(const int2* __restrict__ bins, int bin_stride,
                                              const int* __restrict__ bin_cnt,
                                              float* __restrict__ deg /*in: ovf ew, out: dinv*/,
                                              int* __restrict__ cnt, int2* __restrict__ bucket,
                                              int cap, int* __restrict__ ovf_n,
                                              int* __restrict__ ovf, int ovf_cap, int N) {
    __shared__ float deg_l[256];
    __shared__ int cnt_l[256];
    int b = blockIdx.x, t = threadIdx.x;
    deg_l[t] = 0.f; cnt_l[t] = 0;
    __syncthreads();
    int ne = bin_cnt[b * 16]; if (ne > bin_stride) ne = bin_stride;
    const int2* bp = bins + (size_t)b * bin_stride;
    for (int j = t; j < ne; j += 256) {
        int2 pk = bp[j];
        int s = pk.x & 0xFFFFFF;
        int dl = ((unsigned int)pk.x) >> 24;
        atomicAdd(&deg_l[dl], __int_as_float(pk.y));
        int pos = atomicAdd(&cnt_l[dl], 1);
        int node = b * 256 + dl;
        if (pos < cap) {
            int2 out_pk; out_pk.x = s; out_pk.y = pk.y;
            bucket[(size_t)node * cap + pos] = out_pk;
        } else {
            int o = atomicAdd(ovf_n, 1);
            if (o < ovf_cap) { ovf[3 * o] = s; ovf[3 * o + 1] = node; ovf[3 * o + 2] = pk.y; }
        }
    }
    __syncthreads();
    int node = b * 256 + t;
    if (node < N) {
        float dsum = deg[node] + 1.0f + deg_l[t];
        deg[node] = rsqrtf(dsum);
        int c = cnt_l[t]; if (c > cap) c = cap;
        cnt[node] = c;
    }
}

// ---------------- prep: pad x -> xp[N][8]; B-fragments of W2@We (split bf16); bc ----------------
// Fragment (kk, ct): lane l holds B[32*kk + 8*(l>>4) + i][16*ct + (l&15)], i=0..7.

__global__ void k_prep(const float* __restrict__ x, float* __restrict__ xp, int N, int padxB,
                       const float* __restrict__ W2, const float* __restrict__ We,
                       unsigned short* __restrict__ Bhi, unsigned short* __restrict__ Blo,
                       const float* __restrict__ b2, const float* __restrict__ be,
                       float* __restrict__ bc) {
    int b = blockIdx.x;
    if (b < padxB) {
        int t = b * 256 + threadIdx.x;
        if (t < N * 8) {
            int f = t & 7, i = t >> 3;
            xp[t] = (f < NF0) ? x[i * NF0 + f] : 0.f;
        }
    } else if (b < padxB + 13) {
        int t = (b - padxB) * 256 + threadIdx.x;
        if (t >= 50 * 64) return;
        int fid = t >> 6, lane = t & 63;
        int kk = fid / 5, ct = fid % 5;
        int col = ct * 16 + (lane & 15);
        int row0 = kk * 32 + (lane >> 4) * 8;
        float acc[8] = {0.f, 0.f, 0.f, 0.f, 0.f, 0.f, 0.f, 0.f};
        for (int m = 0; m < F2; ++m) {
            float wv = We[m * F3 + col];
            #pragma unroll
            for (int i = 0; i < 8; ++i)
                acc[i] += W2[(size_t)(row0 + i) * F2 + m] * wv;
        }
        size_t ob = (size_t)t * 8;
        #pragma unroll
        for (int i = 0; i < 8; ++i) {
            float v = acc[i];
            unsigned int ub = __builtin_bit_cast(unsigned int, v);
            float hf = __builtin_bit_cast(float, ub & 0xffff0000u);
            Bhi[ob + i] = (unsigned short)(ub >> 16);
            Blo[ob + i] = f2bf_rne(v - hf);
        }
    } else {
        int j = threadIdx.x;
        if (j < F3) {
            float s = be[j];
            for (int k = 0; k < F2; ++k) s += b2[k] * We[k * F3 + j];
            bc[j] = s;
        }
    }
}

// ---------------- conv1 aggregation via bucket gather (5 features, self folded) ----------------

__global__ void k_aggA(const float* __restrict__ xp, const float* __restrict__ dinv,
                       const int* __restrict__ cnt, const int2* __restrict__ bucket, int cap,
                       float* __restrict__ agg1, int N) {
    int i = blockIdx.x * blockDim.x + threadIdx.x;
    if (i >= N) return;
    float di = dinv[i];
    float sc = di * di;
    float4 xv = *(const float4*)(xp + (size_t)i * 8);
    float x4 = xp[(size_t)i * 8 + 4];
    float a0 = xv.x * sc, a1 = xv.y * sc, a2 = xv.z * sc, a3 = xv.w * sc, a4 = x4 * sc;
    int c = cnt[i];
    const int2* row = bucket + (size_t)i * cap;
    for (int j = 0; j < c; ++j) {
        int2 pk = row[j];
        int s = pk.x;
        float w = di * __int_as_float(pk.y) * dinv[s];
        float4 sv = *(const float4*)(xp + (size_t)s * 8);
        float s4 = xp[(size_t)s * 8 + 4];
        a0 += sv.x * w; a1 += sv.y * w; a2 += sv.z * w; a3 += sv.w * w; a4 += s4 * w;
    }
    float* op = agg1 + (size_t)i * NF0;
    op[0] = a0; op[1] = a1; op[2] = a2; op[3] = a3; op[4] = a4;
}

__global__ void k_fixA(const float* __restrict__ x, const float* __restrict__ dinv,
                       const int* __restrict__ ovf_n, const int* __restrict__ ovf, int ovf_cap,
                       float* __restrict__ agg1) {
    int n = *ovf_n; if (n > ovf_cap) n = ovf_cap;
    for (int j = blockIdx.x * blockDim.x + threadIdx.x; j < n; j += gridDim.x * blockDim.x) {
        int s = ovf[3 * j], d = ovf[3 * j + 1];
        float w = dinv[s] * __int_as_float(ovf[3 * j + 2]) * dinv[d];
        #pragma unroll
        for (int f = 0; f < NF0; ++f)
            atomicAdd(&agg1[(size_t)d * NF0 + f], x[(size_t)s * NF0 + f] * w);
    }
}

// ---------------- fused node transform via MFMA (split-bf16, 3 products) ----------------
// Block 256 = 4 waves; each wave handles 2 sets of 16 nodes (32 nodes/wave, 128/block).
// W1+b1 staged in LDS. B-fragments streamed from global (L2-hot), reused for both sets.
// D layout: col=lane&15, row=(lane>>4)*4+reg. g stored as bf16 (RNE).

__global__ __launch_bounds__(256) void k_node(const float* __restrict__ agg1,
                                              const float* __restrict__ W1,
                                              const float* __restrict__ b1,
                                              const unsigned short* __restrict__ Bhi,
                                              const unsigned short* __restrict__ Blo,
                                              unsigned short* __restrict__ g, int N) {
    __shared__ float W_l[5 * F1 + F1];   // W1 rows then b1
    int tid = threadIdx.x;
    for (int i = tid; i < 480; i += 256) {
        float4 v = (i < 400) ? ((const float4*)W1)[i] : ((const float4*)b1)[i - 400];
        ((float4*)W_l)[i] = v;
    }
    __syncthreads();

    int w = tid >> 6, l = tid & 63;
    int nl = l & 15, kg = l >> 4;
    int base = blockIdx.x * 128 + w * 32;
    int n0 = base + nl, n1 = base + 16 + nl;

    float a0v[5] = {0.f, 0.f, 0.f, 0.f, 0.f};
    float a1v[5] = {0.f, 0.f, 0.f, 0.f, 0.f};
    if (n0 < N) {
        const float* ap = agg1 + (size_t)n0 * NF0;
        #pragma unroll
        for (int j = 0; j < 5; ++j) a0v[j] = ap[j];
    }
    if (n1 < N) {
        const float* ap = agg1 + (size_t)n1 * NF0;
        #pragma unroll
        for (int j = 0; j < 5; ++j) a1v[j] = ap[j];
    }

    f32x4 zero = {0.f, 0.f, 0.f, 0.f};
    f32x4 acc[10] = {zero, zero, zero, zero, zero, zero, zero, zero, zero, zero};
    const bf16x8* bhp = (const bf16x8*)Bhi;
    const bf16x8* blp = (const bf16x8*)Blo;

    #pragma unroll
    for (int kk = 0; kk < 10; ++kk) {
        int k0 = kk * 32 + kg * 8;
        float v0[8], v1[8];
        const float* bb = W_l + 5 * F1 + k0;
        #pragma unroll
        for (int i = 0; i < 8; ++i) { float b = bb[i]; v0[i] = b; v1[i] = b; }
        #pragma unroll
        for (int j = 0; j < 5; ++j) {
            const float* wp = W_l + j * F1 + k0;
            float aj0 = a0v[j], aj1 = a1v[j];
            #pragma unroll
            for (int i = 0; i < 8; ++i) {
                float wv = wp[i];
                v0[i] += aj0 * wv;
                v1[i] += aj1 * wv;
            }
        }
        bf16x8 ah0, al0, ah1, al1;
        #pragma unroll
        for (int i = 0; i < 8; ++i) {
            float t0 = fmaxf(v0[i], 0.f);
            unsigned int u0 = __builtin_bit_cast(unsigned int, t0);
            float h0 = __builtin_bit_cast(float, u0 & 0xffff0000u);
            ah0[i] = (short)(u0 >> 16);
            al0[i] = (short)f2bf_rne(t0 - h0);
            float t1 = fmaxf(v1[i], 0.f);
            unsigned int u1 = __builtin_bit_cast(unsigned int, t1);
            float h1 = __builtin_bit_cast(float, u1 & 0xffff0000u);
            ah1[i] = (short)(u1 >> 16);
            al1[i] = (short)f2bf_rne(t1 - h1);
        }
        #pragma unroll
        for (int ct = 0; ct < 5; ++ct) {
            int idx = (kk * 5 + ct) * 64 + l;
            bf16x8 bh = bhp[idx];
            bf16x8 bl = blp[idx];
            acc[ct] = __builtin_amdgcn_mfma_f32_16x16x32_bf16(ah0, bh, acc[ct], 0, 0, 0);
            acc[ct] = __builtin_amdgcn_mfma_f32_16x16x32_bf16(ah0, bl, acc[ct], 0, 0, 0);
            acc[ct] = __builtin_amdgcn_mfma_f32_16x16x32_bf16(al0, bh, acc[ct], 0, 0, 0);
            acc[5 + ct] = __builtin_amdgcn_mfma_f32_16x16x32_bf16(ah1, bh, acc[5 + ct], 0, 0, 0);
            acc[5 + ct] = __builtin_amdgcn_mfma_f32_16x16x32_bf16(ah1, bl, acc[5 + ct], 0, 0, 0);
            acc[5 + ct] = __builtin_amdgcn_mfma_f32_16x16x32_bf16(al1, bh, acc[5 + ct], 0, 0, 0);
        }
    }

    #pragma unroll
    for (int ct = 0; ct < 5; ++ct) {
        #pragma unroll
        for (int r = 0; r < 4; ++r) {
            int r0 = base + kg * 4 + r;
            if (r0 < N) g[(size_t)r0 * F3 + ct * 16 + nl] = f2bf_rne(acc[ct][r]);
            int r1 = base + 16 + kg * 4 + r;
            if (r1 < N) g[(size_t)r1 * F3 + ct * 16 + nl] = f2bf_rne(acc[5 + ct][r]);
        }
    }
}

// ---------------- conv2 aggregation via bucket gather (bf16 g) -> d_out ----------------
// 2 threads/node; thread h owns 40 consecutive cols (80 B of bf16 per gather).

__global__ void k_aggB(const unsigned short* __restrict__ g, const float* __restrict__ dinv,
                       const float* __restrict__ bc, const int* __restrict__ cnt,
                       const int2* __restrict__ bucket, int cap,
                       float* __restrict__ out, int N) {
    int t = blockIdx.x * blockDim.x + threadIdx.x;
    if (t >= 2 * N) return;
    int i = t >> 1, h = t & 1;
    int cb = h * 40;
    float di = dinv[i];
    float sc = di * di;
    float acc[40];
    {
        const ushortx8* sp = (const ushortx8*)(g + (size_t)i * F3 + cb);
        const float4* bp = (const float4*)(bc + cb);
        #pragma unroll
        for (int q = 0; q < 5; ++q) {
            ushortx8 u = sp[q];
            float4 b0 = bp[2 * q], b1 = bp[2 * q + 1];
            acc[q * 8 + 0] = bf2f(u[0]) * sc + b0.x;
            acc[q * 8 + 1] = bf2f(u[1]) * sc + b0.y;
            acc[q * 8 + 2] = bf2f(u[2]) * sc + b0.z;
            acc[q * 8 + 3] = bf2f(u[3]) * sc + b0.w;
            acc[q * 8 + 4] = bf2f(u[4]) * sc + b1.x;
            acc[q * 8 + 5] = bf2f(u[5]) * sc + b1.y;
            acc[q * 8 + 6] = bf2f(u[6]) * sc + b1.z;
            acc[q * 8 + 7] = bf2f(u[7]) * sc + b1.w;
        }
    }
    int cn = cnt[i];
    const int2* row = bucket + (size_t)i * cap;
    for (int j = 0; j < cn; ++j) {
        int2 pk = row[j];
        int s = pk.x;
        float w = di * __int_as_float(pk.y) * dinv[s];
        const ushortx8* sp = (const ushortx8*)(g + (size_t)s * F3 + cb);
        #pragma unroll
        for (int q = 0; q < 5; ++q) {
            ushortx8 u = sp[q];
            #pragma unroll
            for (int e2 = 0; e2 < 8; ++e2)
                acc[q * 8 + e2] += bf2f(u[e2]) * w;
        }
    }
    float4* op = (float4*)(out + (size_t)i * F3 + cb);
    #pragma unroll
    for (int q = 0; q < 10; ++q) {
        float4 v;
        v.x = acc[q * 4 + 0]; v.y = acc[q * 4 + 1]; v.z = acc[q * 4 + 2]; v.w = acc[q * 4 + 3];
        op[q] = v;
    }
}

__global__ void k_fixB(const unsigned short* __restrict__ g, const float* __restrict__ dinv,
                       const int* __restrict__ ovf_n, const int* __restrict__ ovf, int ovf_cap,
                       float* __restrict__ out) {
    int n = *ovf_n; if (n > ovf_cap) n = ovf_cap;
    for (int j = blockIdx.x * blockDim.x + threadIdx.x; j < n; j += gridDim.x * blockDim.x) {
        int s = ovf[3 * j], d = ovf[3 * j + 1];
        float w = dinv[s] * __int_as_float(ovf[3 * j + 2]) * dinv[d];
        for (int f = 0; f < F3; ++f)
            atomicAdd(&out[(size_t)d * F3 + f], bf2f(g[(size_t)s * F3 + f]) * w);
    }
}

// ---------------- launch ----------------

static inline size_t align256(size_t x) { return (x + 255) & ~(size_t)255; }

extern "C" void kernel_launch(void* const* d_in, const int* in_sizes, int n_in,
                              void* d_out, int out_size, void* d_ws, size_t ws_size,
                              hipStream_t stream) {
    const float* x  = (const float*)d_in[0];
    const void*  ei = d_in[1];
    const float* ew = (const float*)d_in[2];
    const float* W1 = (const float*)d_in[3];
    const float* b1 = (const float*)d_in[4];
    const float* W2 = (const float*)d_in[5];
    const float* b2 = (const float*)d_in[6];
    const float* We = (const float*)d_in[7];
    const float* be = (const float*)d_in[8];
    float* out = (float*)d_out;

    int N = in_sizes[0] / NF0;
    int E = in_sizes[2];

    const int OVF_CAP = 131072;              // 1.5 MB safety net; ~never used
    const int BIN_STRIDE = 4096;             // Poisson(~2046) per bin; P(>4096) ~ 0
    int n_bins = (N + 255) >> 8;

    char* p = (char*)d_ws;
    auto alloc = [&](size_t bytes) { char* r = p; p += align256(bytes); return r; };
    int*   flag  = (int*)alloc(4);
    // zeroed region: deg[N] | ovf_n | pad | bin_cnt[n_bins*16]
    size_t zints = (size_t)N + 16 + (size_t)n_bins * 16;
    int*   zreg  = (int*)alloc(zints * 4);
    float* deg   = (float*)zreg;             // becomes dinv after k_binB
    int*   ovf_n = zreg + N;
    int*   bin_cnt = zreg + N + 16;
    int*   cnt   = (int*)  alloc((size_t)N * 4);
    int*   ovf   = (int*)  alloc((size_t)OVF_CAP * 12);
    int2*  bins  = (int2*) alloc((size_t)n_bins * BIN_STRIDE * 8);
    float* xp    = (float*)alloc((size_t)N * 8 * 4);
    float* agg1  = (float*)alloc((size_t)N * NF0 * 4);
    float* bc    = (float*)alloc((size_t)F3 * 4);
    unsigned short* Bhi = (unsigned short*)alloc((size_t)50 * 64 * 8 * 2);
    unsigned short* Blo = (unsigned short*)alloc((size_t)50 * 64 * 8 * 2);
    unsigned short* g   = (unsigned short*)alloc((size_t)N * F3 * 2);

    // adaptive bucket capacity (8 B/slot); 24 => Poisson(8) overflow ~1e-6/node
    size_t used = (size_t)(p - (char*)d_ws);
    int cap = 24;
    if (ws_size > used) {
        size_t avail = (ws_size - used) / ((size_t)N * 8);
        if (avail < (size_t)cap) cap = (int)avail;
    } else cap = 4;
    if (cap < 4) cap = 4;
    int2* bucket = (int2*)alloc((size_t)N * cap * 8);

    int eb  = (E + 255) / 256;
    int nb1 = (N + 255) / 256;
    int padxB = (N * 8 + 255) / 256;
    int npairs = E < 2048 ? E : 2048;

    hipMemsetAsync(zreg, 0, zints * 4, stream);
    k_detect<<<1, 256, 0, stream>>>((const unsigned int*)ei, npairs, flag);
    k_prep<<<padxB + 14, 256, 0, stream>>>(x, xp, N, padxB, W2, We, Bhi, Blo, b2, be, bc);

    k_binA<<<eb, 256, 0, stream>>>(ei, ew, flag, bin_cnt, bins, BIN_STRIDE, ovf_n, ovf, OVF_CAP, E);
    k_fixdeg<<<16, 256, 0, stream>>>(ovf_n, ovf, OVF_CAP, deg);
    k_binB<<<n_bins, 256, 0, stream>>>(bins, BIN_STRIDE, bin_cnt, deg, cnt, bucket, cap,
                                       ovf_n, ovf, OVF_CAP, N);

    k_aggA<<<nb1, 256, 0, stream>>>(xp, deg, cnt, bucket, cap, agg1, N);
    k_fixA<<<16, 256, 0, stream>>>(x, deg, ovf_n, ovf, OVF_CAP, agg1);
    k_node<<<(N + 127) / 128, 256, 0, stream>>>(agg1, W1, b1, Bhi, Blo, g, N);
    k_aggB<<<(2 * N + 255) / 256, 256, 0, stream>>>(g, deg, bc, cnt, bucket, cap, out, N);
    k_fixB<<<16, 256, 0, stream>>>(g, deg, ovf_n, ovf, OVF_CAP, out);
}

// Round 6
// 189.501 us; speedup vs baseline: 6.8762x; 1.1215x over previous
//
#include <hip/hip_runtime.h>

#define NF0 5
#define F1 320
#define F2 160
#define F3 80

typedef float f32x4 __attribute__((ext_vector_type(4)));
typedef _Float16 f16x8 __attribute__((ext_vector_type(8)));

// ---------------- phase A: bin edges by dst>>8 (1 atomic/edge, clustered writes) ----------------
// bin payload: {src | (dst&255)<<24, ew}. Requires src < 2^24 (N=100000 ok).

__global__ void k_binA(const void* ei, const float* __restrict__ ew, const int* __restrict__ flag,
                       int* __restrict__ bin_cnt /*stride 16 ints*/, int2* __restrict__ bins,
                       int bin_stride, int* __restrict__ ovf_n, int* __restrict__ ovf,
                       int ovf_cap, int E) {
    int e = blockIdx.x * blockDim.x + threadIdx.x;
    if (e >= E) return;
    int s, d;
    if (*flag) {
        const long long* p = (const long long*)ei;
        s = (int)p[e]; d = (int)p[E + e];
    } else {
        const int* p = (const int*)ei;
        s = p[e]; d = p[E + e];
    }
    float w = ew[e];
    int b = d >> 8;
    int pos = atomicAdd(&bin_cnt[b * 16], 1);
    if (pos < bin_stride) {
        int2 pk;
        pk.x = s | ((d & 255) << 24);
        pk.y = __float_as_int(w);
        bins[(size_t)b * bin_stride + pos] = pk;
    } else {
        int o = atomicAdd(ovf_n, 1);
        if (o < ovf_cap) {
            ovf[3 * o] = s; ovf[3 * o + 1] = d; ovf[3 * o + 2] = __float_as_int(w);
        }
    }
}

// overflow edges' ew into deg (deg pre-zeroed); runs between binA and binB
__global__ void k_fixdeg(const int* __restrict__ ovf_n, const int* __restrict__ ovf, int ovf_cap,
                         float* __restrict__ deg) {
    int n = *ovf_n; if (n > ovf_cap) n = ovf_cap;
    for (int j = blockIdx.x * blockDim.x + threadIdx.x; j < n; j += gridDim.x * blockDim.x)
        atomicAdd(&deg[ovf[3 * j + 1]], __int_as_float(ovf[3 * j + 2]));
}

// ---------------- phase B: per-bin LDS cnt/deg, scatter to bucket, dinv in-block ----------------

__global__ __launch_bounds__(256) void k_binB(const int2* __restrict__ bins, int bin_stride,
                                              const int* __restrict__ bin_cnt,
                                              float* __restrict__ deg /*in: ovf ew, out: dinv*/,
                                              int* __restrict__ cnt, int2* __restrict__ bucket,
                                              int cap, int* __restrict__ ovf_n,
                                              int* __restrict__ ovf, int ovf_cap, int N) {
    __shared__ float deg_l[256];
    __shared__ int cnt_l[256];
    int b = blockIdx.x, t = threadIdx.x;
    deg_l[t] = 0.f; cnt_l[t] = 0;
    __syncthreads();
    int ne = bin_cnt[b * 16]; if (ne > bin_stride) ne = bin_stride;
    const int2* bp = bins + (size_t)b * bin_stride;
    for (int j = t; j < ne; j += 256) {
        int2 pk = bp[j];
        int s = pk.x & 0xFFFFFF;
        int dl = ((unsigned int)pk.x) >> 24;
        atomicAdd(&deg_l[dl], __int_as_float(pk.y));
        int pos = atomicAdd(&cnt_l[dl], 1);
        int node = b * 256 + dl;
        if (pos < cap) {
            int2 out_pk; out_pk.x = s; out_pk.y = pk.y;
            bucket[(size_t)node * cap + pos] = out_pk;
        } else {
            int o = atomicAdd(ovf_n, 1);
            if (o < ovf_cap) { ovf[3 * o] = s; ovf[3 * o + 1] = node; ovf[3 * o + 2] = pk.y; }
        }
    }
    __syncthreads();
    int node = b * 256 + t;
    if (node < N) {
        float dsum = deg[node] + 1.0f + deg_l[t];
        deg[node] = rsqrtf(dsum);
        int c = cnt_l[t]; if (c > cap) c = cap;
        cnt[node] = c;
    }
}

// ---------------- prep: pad x -> xp[N][8]; B-frags of f16(W2@We); bc; ei width detect ----------------
// Fragment (kk, ct): lane l holds B[32*kk + 8*(l>>4) + i][16*ct + (l&15)], i=0..7.

__global__ void k_prep(const float* __restrict__ x, float* __restrict__ xp, int N, int padxB,
                       const float* __restrict__ W2, const float* __restrict__ We,
                       _Float16* __restrict__ Bh,
                       const float* __restrict__ b2, const float* __restrict__ be,
                       float* __restrict__ bc,
                       const unsigned int* __restrict__ ei32, int E, int* __restrict__ flag) {
    __shared__ int ok;
    int b = blockIdx.x;
    if (b < padxB) {
        int t = b * 256 + threadIdx.x;
        if (t < N * 8) {
            int f = t & 7, i = t >> 3;
            xp[t] = (f < NF0) ? x[i * NF0 + f] : 0.f;
        }
    } else if (b < padxB + 13) {
        int t = (b - padxB) * 256 + threadIdx.x;
        if (t >= 50 * 64) return;
        int fid = t >> 6, lane = t & 63;
        int kk = fid / 5, ct = fid % 5;
        int col = ct * 16 + (lane & 15);
        int row0 = kk * 32 + (lane >> 4) * 8;
        float acc[8] = {0.f, 0.f, 0.f, 0.f, 0.f, 0.f, 0.f, 0.f};
        for (int m = 0; m < F2; ++m) {
            float wv = We[m * F3 + col];
            #pragma unroll
            for (int i = 0; i < 8; ++i)
                acc[i] += W2[(size_t)(row0 + i) * F2 + m] * wv;
        }
        size_t ob = (size_t)t * 8;
        #pragma unroll
        for (int i = 0; i < 8; ++i)
            Bh[ob + i] = (_Float16)acc[i];   // RNE
    } else if (b == padxB + 13) {
        int j = threadIdx.x;
        if (j < F3) {
            float s = be[j];
            for (int k = 0; k < F2; ++k) s += b2[k] * We[k * F3 + j];
            bc[j] = s;
        }
    } else {
        if (threadIdx.x == 0) ok = 1;
        __syncthreads();
        int npairs = E < 2048 ? E : 2048;
        for (int i = threadIdx.x; i < npairs; i += blockDim.x)
            if (ei32[2 * i + 1] != 0u) ok = 0;   // benign race
        __syncthreads();
        if (threadIdx.x == 0) *flag = ok;        // 1 => int64 storage, 0 => int32
    }
}

// ---------------- conv1 aggregation via bucket gather; folds w back into bucket ----------------

__global__ void k_aggA(const float* __restrict__ xp, const float* __restrict__ dinv,
                       const int* __restrict__ cnt, int2* __restrict__ bucket, int cap,
                       float* __restrict__ agg1, int N) {
    int i = blockIdx.x * blockDim.x + threadIdx.x;
    if (i >= N) return;
    float di = dinv[i];
    float sc = di * di;
    float4 xv = *(const float4*)(xp + (size_t)i * 8);
    float x4 = xp[(size_t)i * 8 + 4];
    float a0 = xv.x * sc, a1 = xv.y * sc, a2 = xv.z * sc, a3 = xv.w * sc, a4 = x4 * sc;
    int c = cnt[i];
    int2* row = bucket + (size_t)i * cap;
    for (int j = 0; j < c; ++j) {
        int2 pk = row[j];
        int s = pk.x;
        float w = di * __int_as_float(pk.y) * dinv[s];
        row[j].y = __float_as_int(w);          // pre-fold for aggB
        float4 sv = *(const float4*)(xp + (size_t)s * 8);
        float s4 = xp[(size_t)s * 8 + 4];
        a0 += sv.x * w; a1 += sv.y * w; a2 += sv.z * w; a3 += sv.w * w; a4 += s4 * w;
    }
    float* op = agg1 + (size_t)i * NF0;
    op[0] = a0; op[1] = a1; op[2] = a2; op[3] = a3; op[4] = a4;
}

__global__ void k_fixA(const float* __restrict__ x, const float* __restrict__ dinv,
                       const int* __restrict__ ovf_n, int* __restrict__ ovf, int ovf_cap,
                       float* __restrict__ agg1) {
    int n = *ovf_n; if (n > ovf_cap) n = ovf_cap;
    for (int j = blockIdx.x * blockDim.x + threadIdx.x; j < n; j += gridDim.x * blockDim.x) {
        int s = ovf[3 * j], d = ovf[3 * j + 1];
        float w = dinv[s] * __int_as_float(ovf[3 * j + 2]) * dinv[d];
        ovf[3 * j + 2] = __float_as_int(w);    // pre-fold for fixB
        #pragma unroll
        for (int f = 0; f < NF0; ++f)
            atomicAdd(&agg1[(size_t)d * NF0 + f], x[(size_t)s * NF0 + f] * w);
    }
}

// ---------------- fused node transform via MFMA (f16 2-product: t*B = th*Bh + tl*Bh) ----------------
// Block 256 = 4 waves; each wave handles 2 sets of 16 nodes. W1+b1 in LDS.
// B single f16 array streamed from L2 (50 KB/wave). D: col=lane&15, row=(lane>>4)*4+reg.
// g stored as f16 (RNE), error 2^-11 vs bf16's 2^-8.

__global__ __launch_bounds__(256) void k_node(const float* __restrict__ agg1,
                                              const float* __restrict__ W1,
                                              const float* __restrict__ b1,
                                              const _Float16* __restrict__ Bh,
                                              _Float16* __restrict__ g, int N) {
    __shared__ float W_l[6 * F1];   // W1 rows then b1
    int tid = threadIdx.x;
    for (int i = tid; i < 480; i += 256) {
        float4 v = (i < 400) ? ((const float4*)W1)[i] : ((const float4*)b1)[i - 400];
        ((float4*)W_l)[i] = v;
    }
    __syncthreads();

    int w = tid >> 6, l = tid & 63;
    int nl = l & 15, kg = l >> 4;
    int base = blockIdx.x * 128 + w * 32;
    int n0 = base + nl, n1 = base + 16 + nl;

    float a0v[5] = {0.f, 0.f, 0.f, 0.f, 0.f};
    float a1v[5] = {0.f, 0.f, 0.f, 0.f, 0.f};
    if (n0 < N) {
        const float* ap = agg1 + (size_t)n0 * NF0;
        #pragma unroll
        for (int j = 0; j < 5; ++j) a0v[j] = ap[j];
    }
    if (n1 < N) {
        const float* ap = agg1 + (size_t)n1 * NF0;
        #pragma unroll
        for (int j = 0; j < 5; ++j) a1v[j] = ap[j];
    }

    f32x4 zero = {0.f, 0.f, 0.f, 0.f};
    f32x4 acc[10] = {zero, zero, zero, zero, zero, zero, zero, zero, zero, zero};
    const f16x8* bhp = (const f16x8*)Bh;

    #pragma unroll
    for (int kk = 0; kk < 10; ++kk) {
        int k0 = kk * 32 + kg * 8;
        float v0[8], v1[8];
        const float* bb = W_l + 5 * F1 + k0;
        #pragma unroll
        for (int i = 0; i < 8; ++i) { float b = bb[i]; v0[i] = b; v1[i] = b; }
        #pragma unroll
        for (int j = 0; j < 5; ++j) {
            const float* wp = W_l + j * F1 + k0;
            float aj0 = a0v[j], aj1 = a1v[j];
            #pragma unroll
            for (int i = 0; i < 8; ++i) {
                float wv = wp[i];
                v0[i] += aj0 * wv;
                v1[i] += aj1 * wv;
            }
        }
        f16x8 ah0, al0, ah1, al1;
        #pragma unroll
        for (int i = 0; i < 8; ++i) {
            float t0 = fmaxf(v0[i], 0.f);
            _Float16 h0 = (_Float16)t0;
            ah0[i] = h0;
            al0[i] = (_Float16)(t0 - (float)h0);
            float t1 = fmaxf(v1[i], 0.f);
            _Float16 h1 = (_Float16)t1;
            ah1[i] = h1;
            al1[i] = (_Float16)(t1 - (float)h1);
        }
        #pragma unroll
        for (int ct = 0; ct < 5; ++ct) {
            f16x8 bf = bhp[(kk * 5 + ct) * 64 + l];
            acc[ct] = __builtin_amdgcn_mfma_f32_16x16x32_f16(ah0, bf, acc[ct], 0, 0, 0);
            acc[ct] = __builtin_amdgcn_mfma_f32_16x16x32_f16(al0, bf, acc[ct], 0, 0, 0);
            acc[5 + ct] = __builtin_amdgcn_mfma_f32_16x16x32_f16(ah1, bf, acc[5 + ct], 0, 0, 0);
            acc[5 + ct] = __builtin_amdgcn_mfma_f32_16x16x32_f16(al1, bf, acc[5 + ct], 0, 0, 0);
        }
    }

    #pragma unroll
    for (int ct = 0; ct < 5; ++ct) {
        #pragma unroll
        for (int r = 0; r < 4; ++r) {
            int r0 = base + kg * 4 + r;
            if (r0 < N) g[(size_t)r0 * F3 + ct * 16 + nl] = (_Float16)acc[ct][r];
            int r1 = base + 16 + kg * 4 + r;
            if (r1 < N) g[(size_t)r1 * F3 + ct * 16 + nl] = (_Float16)acc[5 + ct][r];
        }
    }
}

// ---------------- conv2 aggregation via bucket gather (f16 g, pre-folded w) -> d_out ----------------
// 5 threads/node; thread c owns 16 consecutive cols (32 B of f16 per gather).

__global__ __launch_bounds__(256) void k_aggB(const _Float16* __restrict__ g,
                                              const float* __restrict__ dinv,
                                              const float* __restrict__ bc,
                                              const int* __restrict__ cnt,
                                              const int2* __restrict__ bucket, int cap,
                                              float* __restrict__ out, int N) {
    int t = blockIdx.x * blockDim.x + threadIdx.x;
    if (t >= 5 * N) return;
    int i = t / 5;
    int c = (t - i * 5) << 4;    // col base: 0,16,32,48,64
    float di = dinv[i];
    float sc = di * di;
    float acc[16];
    {
        const f16x8* sp = (const f16x8*)(g + (size_t)i * F3 + c);
        f16x8 u0 = sp[0], u1 = sp[1];
        const float4* bp = (const float4*)(bc + c);
        float4 q0 = bp[0], q1 = bp[1], q2 = bp[2], q3 = bp[3];
        acc[0]  = (float)u0[0] * sc + q0.x;  acc[1]  = (float)u0[1] * sc + q0.y;
        acc[2]  = (float)u0[2] * sc + q0.z;  acc[3]  = (float)u0[3] * sc + q0.w;
        acc[4]  = (float)u0[4] * sc + q1.x;  acc[5]  = (float)u0[5] * sc + q1.y;
        acc[6]  = (float)u0[6] * sc + q1.z;  acc[7]  = (float)u0[7] * sc + q1.w;
        acc[8]  = (float)u1[0] * sc + q2.x;  acc[9]  = (float)u1[1] * sc + q2.y;
        acc[10] = (float)u1[2] * sc + q2.z;  acc[11] = (float)u1[3] * sc + q2.w;
        acc[12] = (float)u1[4] * sc + q3.x;  acc[13] = (float)u1[5] * sc + q3.y;
        acc[14] = (float)u1[6] * sc + q3.z;  acc[15] = (float)u1[7] * sc + q3.w;
    }
    int cn = cnt[i];
    const int2* row = bucket + (size_t)i * cap;
    #pragma unroll 2
    for (int j = 0; j < cn; ++j) {
        int2 pk = row[j];
        float w = __int_as_float(pk.y);      // pre-folded dinv[d]*ew*dinv[s]
        const f16x8* sp = (const f16x8*)(g + (size_t)pk.x * F3 + c);
        f16x8 a = sp[0], b8 = sp[1];
        #pragma unroll
        for (int e = 0; e < 8; ++e) {
            acc[e]     += (float)a[e]  * w;
            acc[8 + e] += (float)b8[e] * w;
        }
    }
    float4* op = (float4*)(out + (size_t)i * F3 + c);
    #pragma unroll
    for (int q = 0; q < 4; ++q) {
        float4 v;
        v.x = acc[q * 4 + 0]; v.y = acc[q * 4 + 1]; v.z = acc[q * 4 + 2]; v.w = acc[q * 4 + 3];
        op[q] = v;
    }
}

__global__ void k_fixB(const _Float16* __restrict__ g, const float* __restrict__ dinv,
                       const int* __restrict__ ovf_n, const int* __restrict__ ovf, int ovf_cap,
                       float* __restrict__ out) {
    int n = *ovf_n; if (n > ovf_cap) n = ovf_cap;
    for (int j = blockIdx.x * blockDim.x + threadIdx.x; j < n; j += gridDim.x * blockDim.x) {
        int s = ovf[3 * j], d = ovf[3 * j + 1];
        float w = __int_as_float(ovf[3 * j + 2]);   // pre-folded by fixA
        for (int f = 0; f < F3; ++f)
            atomicAdd(&out[(size_t)d * F3 + f], (float)g[(size_t)s * F3 + f] * w);
    }
}

// ---------------- launch ----------------

static inline size_t align256(size_t x) { return (x + 255) & ~(size_t)255; }

extern "C" void kernel_launch(void* const* d_in, const int* in_sizes, int n_in,
                              void* d_out, int out_size, void* d_ws, size_t ws_size,
                              hipStream_t stream) {
    const float* x  = (const float*)d_in[0];
    const void*  ei = d_in[1];
    const float* ew = (const float*)d_in[2];
    const float* W1 = (const float*)d_in[3];
    const float* b1 = (const float*)d_in[4];
    const float* W2 = (const float*)d_in[5];
    const float* b2 = (const float*)d_in[6];
    const float* We = (const float*)d_in[7];
    const float* be = (const float*)d_in[8];
    float* out = (float*)d_out;

    int N = in_sizes[0] / NF0;
    int E = in_sizes[2];

    const int OVF_CAP = 131072;              // safety net; ~never used
    const int BIN_STRIDE = 4096;             // Poisson(~2046) per bin; P(>4096) ~ 0
    int n_bins = (N + 255) >> 8;

    char* p = (char*)d_ws;
    auto alloc = [&](size_t bytes) { char* r = p; p += align256(bytes); return r; };
    int*   flag  = (int*)alloc(4);
    // zeroed region: deg[N] | ovf_n | pad | bin_cnt[n_bins*16]
    size_t zints = (size_t)N + 16 + (size_t)n_bins * 16;
    int*   zreg  = (int*)alloc(zints * 4);
    float* deg   = (float*)zreg;             // becomes dinv after k_binB
    int*   ovf_n = zreg + N;
    int*   bin_cnt = zreg + N + 16;
    int*   cnt   = (int*)  alloc((size_t)N * 4);
    int*   ovf   = (int*)  alloc((size_t)OVF_CAP * 12);
    int2*  bins  = (int2*) alloc((size_t)n_bins * BIN_STRIDE * 8);
    float* xp    = (float*)alloc((size_t)N * 8 * 4);
    float* agg1  = (float*)alloc((size_t)N * NF0 * 4);
    float* bc    = (float*)alloc((size_t)F3 * 4);
    _Float16* Bh = (_Float16*)alloc((size_t)50 * 64 * 8 * 2);
    _Float16* g  = (_Float16*)alloc((size_t)N * F3 * 2);

    // adaptive bucket capacity (8 B/slot); 24 => Poisson(8) overflow ~1e-6/node
    size_t used = (size_t)(p - (char*)d_ws);
    int cap = 24;
    if (ws_size > used) {
        size_t avail = (ws_size - used) / ((size_t)N * 8);
        if (avail < (size_t)cap) cap = (int)avail;
    } else cap = 4;
    if (cap < 4) cap = 4;
    int2* bucket = (int2*)alloc((size_t)N * cap * 8);

    int eb  = (E + 255) / 256;
    int nb1 = (N + 255) / 256;
    int padxB = (N * 8 + 255) / 256;

    hipMemsetAsync(zreg, 0, zints * 4, stream);
    k_prep<<<padxB + 15, 256, 0, stream>>>(x, xp, N, padxB, W2, We, Bh, b2, be, bc,
                                           (const unsigned int*)ei, E, flag);

    k_binA<<<eb, 256, 0, stream>>>(ei, ew, flag, bin_cnt, bins, BIN_STRIDE, ovf_n, ovf, OVF_CAP, E);
    k_fixdeg<<<16, 256, 0, stream>>>(ovf_n, ovf, OVF_CAP, deg);
    k_binB<<<n_bins, 256, 0, stream>>>(bins, BIN_STRIDE, bin_cnt, deg, cnt, bucket, cap,
                                       ovf_n, ovf, OVF_CAP, N);

    k_aggA<<<nb1, 256, 0, stream>>>(xp, deg, cnt, bucket, cap, agg1, N);
    k_fixA<<<16, 256, 0, stream>>>(x, deg, ovf_n, ovf, OVF_CAP, agg1);
    k_node<<<(N + 127) / 128, 256, 0, stream>>>(agg1, W1, b1, Bh, g, N);
    k_aggB<<<(5 * N + 255) / 256, 256, 0, stream>>>(g, deg, bc, cnt, bucket, cap, out, N);
    k_fixB<<<16, 256, 0, stream>>>(g, deg, ovf_n, ovf, OVF_CAP, out);
}

// Round 7
// 189.291 us; speedup vs baseline: 6.8838x; 1.0011x over previous
//
#include <hip/hip_runtime.h>

#define NF0 5
#define F1 320
#define F2 160
#define F3 80

typedef float f32x4 __attribute__((ext_vector_type(4)));
typedef _Float16 f16x8 __attribute__((ext_vector_type(8)));

// ---------------- phase A: bin edges by dst>>8 (1 atomic/edge, clustered writes) ----------------
// bin payload: {src | (dst&255)<<24, ew}. Requires src < 2^24 (N=100000 ok).

__global__ void k_binA(const void* ei, const float* __restrict__ ew, const int* __restrict__ flag,
                       int* __restrict__ bin_cnt /*stride 16 ints*/, int2* __restrict__ bins,
                       int bin_stride, int* __restrict__ ovf_n, int* __restrict__ ovf,
                       int ovf_cap, int E) {
    int e = blockIdx.x * blockDim.x + threadIdx.x;
    if (e >= E) return;
    int s, d;
    if (*flag) {
        const long long* p = (const long long*)ei;
        s = (int)p[e]; d = (int)p[E + e];
    } else {
        const int* p = (const int*)ei;
        s = p[e]; d = p[E + e];
    }
    float w = ew[e];
    int b = d >> 8;
    int pos = atomicAdd(&bin_cnt[b * 16], 1);
    if (pos < bin_stride) {
        int2 pk;
        pk.x = s | ((d & 255) << 24);
        pk.y = __float_as_int(w);
        bins[(size_t)b * bin_stride + pos] = pk;
    } else {
        int o = atomicAdd(ovf_n, 1);
        if (o < ovf_cap) {
            ovf[3 * o] = s; ovf[3 * o + 1] = d; ovf[3 * o + 2] = __float_as_int(w);
        }
    }
}

// binA-overflow edges' ew into deg (deg pre-zeroed); runs before binB1
__global__ void k_fixdeg(const int* __restrict__ ovf_n, const int* __restrict__ ovf, int ovf_cap,
                         float* __restrict__ deg) {
    int n = *ovf_n; if (n > ovf_cap) n = ovf_cap;
    for (int j = blockIdx.x * blockDim.x + threadIdx.x; j < n; j += gridDim.x * blockDim.x)
        atomicAdd(&deg[ovf[3 * j + 1]], __int_as_float(ovf[3 * j + 2]));
}

// ---------------- binB1: per-bin LDS degree accumulation -> dinv ----------------

__global__ __launch_bounds__(256) void k_binB1(const int2* __restrict__ bins, int bin_stride,
                                               const int* __restrict__ bin_cnt,
                                               float* __restrict__ deg /*in: ovf ew, out: dinv*/,
                                               int N) {
    __shared__ float deg_l[256];
    int b = blockIdx.x, t = threadIdx.x;
    deg_l[t] = 0.f;
    __syncthreads();
    int ne = bin_cnt[b * 16]; if (ne > bin_stride) ne = bin_stride;
    const int2* bp = bins + (size_t)b * bin_stride;
    for (int j = t; j < ne; j += 256) {
        int2 pk = bp[j];
        atomicAdd(&deg_l[((unsigned int)pk.x) >> 24], __int_as_float(pk.y));
    }
    __syncthreads();
    int node = b * 256 + t;
    if (node < N) deg[node] = rsqrtf(deg[node] + 1.0f + deg_l[t]);
}

// ---------------- binB2: fold w, scatter bucket, conv1-aggregate in LDS ----------------
// One block per bin. Edge-parallel coalesced pass over bins; acc_l holds agg1 for
// the bin's 256 nodes (5 f32 each). Bucket payload gets PRE-FOLDED w for aggB.

__global__ __launch_bounds__(256) void k_binB2(const int2* __restrict__ bins, int bin_stride,
                                               const int* __restrict__ bin_cnt,
                                               const float* __restrict__ dinv,
                                               const float* __restrict__ xp,
                                               int* __restrict__ cnt, int2* __restrict__ bucket,
                                               int cap, float* __restrict__ agg1,
                                               int* __restrict__ ovf_n, int* __restrict__ ovf,
                                               int ovf_cap, int N) {
    __shared__ int cnt_l[256];
    __shared__ float dinv_l[256];
    __shared__ float acc_l[256 * NF0];
    int b = blockIdx.x, t = threadIdx.x;
    cnt_l[t] = 0;
    int node0 = b * 256 + t;
    dinv_l[t] = (node0 < N) ? dinv[node0] : 0.f;
    for (int q = t; q < 256 * NF0; q += 256) acc_l[q] = 0.f;
    __syncthreads();

    int ne = bin_cnt[b * 16]; if (ne > bin_stride) ne = bin_stride;
    const int2* bp = bins + (size_t)b * bin_stride;
    for (int j = t; j < ne; j += 256) {
        int2 pk = bp[j];
        int s = pk.x & 0xFFFFFF;
        int dl = ((unsigned int)pk.x) >> 24;
        float w = dinv[s] * __int_as_float(pk.y) * dinv_l[dl];
        int node = b * 256 + dl;
        int pos = atomicAdd(&cnt_l[dl], 1);
        if (pos < cap) {
            int2 out_pk; out_pk.x = s; out_pk.y = __float_as_int(w);
            bucket[(size_t)node * cap + pos] = out_pk;
        } else {
            int o = atomicAdd(ovf_n, 1);
            if (o < ovf_cap) { ovf[3 * o] = s; ovf[3 * o + 1] = node; ovf[3 * o + 2] = pk.y; }
        }
        float4 sv = *(const float4*)(xp + (size_t)s * 8);
        float s4 = xp[(size_t)s * 8 + 4];
        atomicAdd(&acc_l[dl * NF0 + 0], sv.x * w);
        atomicAdd(&acc_l[dl * NF0 + 1], sv.y * w);
        atomicAdd(&acc_l[dl * NF0 + 2], sv.z * w);
        atomicAdd(&acc_l[dl * NF0 + 3], sv.w * w);
        atomicAdd(&acc_l[dl * NF0 + 4], s4 * w);
    }
    __syncthreads();

    if (node0 < N) {
        float di = dinv_l[t];
        float sc = di * di;
        float4 xv = *(const float4*)(xp + (size_t)node0 * 8);
        float x4 = xp[(size_t)node0 * 8 + 4];
        float* op = agg1 + (size_t)node0 * NF0;
        op[0] = acc_l[t * NF0 + 0] + xv.x * sc;
        op[1] = acc_l[t * NF0 + 1] + xv.y * sc;
        op[2] = acc_l[t * NF0 + 2] + xv.z * sc;
        op[3] = acc_l[t * NF0 + 3] + xv.w * sc;
        op[4] = acc_l[t * NF0 + 4] + x4 * sc;
        int c = cnt_l[t]; if (c > cap) c = cap;
        cnt[node0] = c;
    }
}

// ---------------- prep: pad x -> xp[N][8]; B-frags of f16(W2@We); bc; ei width detect ----------------
// Fragment (kk, ct): lane l holds B[32*kk + 8*(l>>4) + i][16*ct + (l&15)], i=0..7.

__global__ void k_prep(const float* __restrict__ x, float* __restrict__ xp, int N, int padxB,
                       const float* __restrict__ W2, const float* __restrict__ We,
                       _Float16* __restrict__ Bh,
                       const float* __restrict__ b2, const float* __restrict__ be,
                       float* __restrict__ bc,
                       const unsigned int* __restrict__ ei32, int E, int* __restrict__ flag) {
    __shared__ int ok;
    int b = blockIdx.x;
    if (b < padxB) {
        int t = b * 256 + threadIdx.x;
        if (t < N * 8) {
            int f = t & 7, i = t >> 3;
            xp[t] = (f < NF0) ? x[i * NF0 + f] : 0.f;
        }
    } else if (b < padxB + 13) {
        int t = (b - padxB) * 256 + threadIdx.x;
        if (t >= 50 * 64) return;
        int fid = t >> 6, lane = t & 63;
        int kk = fid / 5, ct = fid % 5;
        int col = ct * 16 + (lane & 15);
        int row0 = kk * 32 + (lane >> 4) * 8;
        float acc[8] = {0.f, 0.f, 0.f, 0.f, 0.f, 0.f, 0.f, 0.f};
        for (int m = 0; m < F2; ++m) {
            float wv = We[m * F3 + col];
            #pragma unroll
            for (int i = 0; i < 8; ++i)
                acc[i] += W2[(size_t)(row0 + i) * F2 + m] * wv;
        }
        size_t ob = (size_t)t * 8;
        #pragma unroll
        for (int i = 0; i < 8; ++i)
            Bh[ob + i] = (_Float16)acc[i];   // RNE
    } else if (b == padxB + 13) {
        int j = threadIdx.x;
        if (j < F3) {
            float s = be[j];
            for (int k = 0; k < F2; ++k) s += b2[k] * We[k * F3 + j];
            bc[j] = s;
        }
    } else {
        if (threadIdx.x == 0) ok = 1;
        __syncthreads();
        int npairs = E < 2048 ? E : 2048;
        for (int i = threadIdx.x; i < npairs; i += blockDim.x)
            if (ei32[2 * i + 1] != 0u) ok = 0;   // benign race
        __syncthreads();
        if (threadIdx.x == 0) *flag = ok;        // 1 => int64 storage, 0 => int32
    }
}

// binA/binB2-overflow edges into agg1 (after binB2); re-folds w for fixB
__global__ void k_fixA(const float* __restrict__ x, const float* __restrict__ dinv,
                       const int* __restrict__ ovf_n, int* __restrict__ ovf, int ovf_cap,
                       float* __restrict__ agg1) {
    int n = *ovf_n; if (n > ovf_cap) n = ovf_cap;
    for (int j = blockIdx.x * blockDim.x + threadIdx.x; j < n; j += gridDim.x * blockDim.x) {
        int s = ovf[3 * j], d = ovf[3 * j + 1];
        float w = dinv[s] * __int_as_float(ovf[3 * j + 2]) * dinv[d];
        ovf[3 * j + 2] = __float_as_int(w);    // pre-fold for fixB
        #pragma unroll
        for (int f = 0; f < NF0; ++f)
            atomicAdd(&agg1[(size_t)d * NF0 + f], x[(size_t)s * NF0 + f] * w);
    }
}

// ---------------- fused node transform via MFMA (f16 2-product: t*B = th*B + tl*B) ----------------
// Block 256 = 4 waves; ONE set of 16 nodes per wave (maximize wave count: grid=N/64,
// ~24 waves/CU for latency hiding of the L2 B-fragment streams). W1+b1 in LDS.
// D: col=lane&15, row=(lane>>4)*4+reg. g stored as f16 (RNE).

__global__ __launch_bounds__(256) void k_node(const float* __restrict__ agg1,
                                              const float* __restrict__ W1,
                                              const float* __restrict__ b1,
                                              const _Float16* __restrict__ Bh,
                                              _Float16* __restrict__ g, int N) {
    __shared__ float W_l[6 * F1];   // W1 rows then b1
    int tid = threadIdx.x;
    for (int i = tid; i < 480; i += 256) {
        float4 v = (i < 400) ? ((const float4*)W1)[i] : ((const float4*)b1)[i - 400];
        ((float4*)W_l)[i] = v;
    }
    __syncthreads();

    int w = tid >> 6, l = tid & 63;
    int nl = l & 15, kg = l >> 4;
    int base = blockIdx.x * 64 + w * 16;
    int n0 = base + nl;

    float a0v[5] = {0.f, 0.f, 0.f, 0.f, 0.f};
    if (n0 < N) {
        const float* ap = agg1 + (size_t)n0 * NF0;
        #pragma unroll
        for (int j = 0; j < 5; ++j) a0v[j] = ap[j];
    }

    f32x4 zero = {0.f, 0.f, 0.f, 0.f};
    f32x4 acc[5] = {zero, zero, zero, zero, zero};
    const f16x8* bhp = (const f16x8*)Bh;

    #pragma unroll
    for (int kk = 0; kk < 10; ++kk) {
        int k0 = kk * 32 + kg * 8;
        float v0[8];
        const float* bb = W_l + 5 * F1 + k0;
        #pragma unroll
        for (int i = 0; i < 8; ++i) v0[i] = bb[i];
        #pragma unroll
        for (int j = 0; j < 5; ++j) {
            const float* wp = W_l + j * F1 + k0;
            float aj0 = a0v[j];
            #pragma unroll
            for (int i = 0; i < 8; ++i) v0[i] += aj0 * wp[i];
        }
        f16x8 ah0, al0;
        #pragma unroll
        for (int i = 0; i < 8; ++i) {
            float t0 = fmaxf(v0[i], 0.f);
            _Float16 h0 = (_Float16)t0;
            ah0[i] = h0;
            al0[i] = (_Float16)(t0 - (float)h0);
        }
        #pragma unroll
        for (int ct = 0; ct < 5; ++ct) {
            f16x8 bf = bhp[(kk * 5 + ct) * 64 + l];
            acc[ct] = __builtin_amdgcn_mfma_f32_16x16x32_f16(ah0, bf, acc[ct], 0, 0, 0);
            acc[ct] = __builtin_amdgcn_mfma_f32_16x16x32_f16(al0, bf, acc[ct], 0, 0, 0);
        }
    }

    #pragma unroll
    for (int ct = 0; ct < 5; ++ct) {
        #pragma unroll
        for (int r = 0; r < 4; ++r) {
            int r0 = base + kg * 4 + r;
            if (r0 < N) g[(size_t)r0 * F3 + ct * 16 + nl] = (_Float16)acc[ct][r];
        }
    }
}

// ---------------- conv2 aggregation via bucket gather (f16 g, pre-folded w) -> d_out ----------------
// 5 threads/node; thread c owns 16 consecutive cols (32 B of f16 per gather).

__global__ __launch_bounds__(256) void k_aggB(const _Float16* __restrict__ g,
                                              const float* __restrict__ dinv,
                                              const float* __restrict__ bc,
                                              const int* __restrict__ cnt,
                                              const int2* __restrict__ bucket, int cap,
                                              float* __restrict__ out, int N) {
    int t = blockIdx.x * blockDim.x + threadIdx.x;
    if (t >= 5 * N) return;
    int i = t / 5;
    int c = (t - i * 5) << 4;    // col base: 0,16,32,48,64
    float di = dinv[i];
    float sc = di * di;
    float acc[16];
    {
        const f16x8* sp = (const f16x8*)(g + (size_t)i * F3 + c);
        f16x8 u0 = sp[0], u1 = sp[1];
        const float4* bp = (const float4*)(bc + c);
        float4 q0 = bp[0], q1 = bp[1], q2 = bp[2], q3 = bp[3];
        acc[0]  = (float)u0[0] * sc + q0.x;  acc[1]  = (float)u0[1] * sc + q0.y;
        acc[2]  = (float)u0[2] * sc + q0.z;  acc[3]  = (float)u0[3] * sc + q0.w;
        acc[4]  = (float)u0[4] * sc + q1.x;  acc[5]  = (float)u0[5] * sc + q1.y;
        acc[6]  = (float)u0[6] * sc + q1.z;  acc[7]  = (float)u0[7] * sc + q1.w;
        acc[8]  = (float)u1[0] * sc + q2.x;  acc[9]  = (float)u1[1] * sc + q2.y;
        acc[10] = (float)u1[2] * sc + q2.z;  acc[11] = (float)u1[3] * sc + q2.w;
        acc[12] = (float)u1[4] * sc + q3.x;  acc[13] = (float)u1[5] * sc + q3.y;
        acc[14] = (float)u1[6] * sc + q3.z;  acc[15] = (float)u1[7] * sc + q3.w;
    }
    int cn = cnt[i];
    const int2* row = bucket + (size_t)i * cap;
    #pragma unroll 2
    for (int j = 0; j < cn; ++j) {
        int2 pk = row[j];
        float w = __int_as_float(pk.y);      // pre-folded dinv[d]*ew*dinv[s]
        const f16x8* sp = (const f16x8*)(g + (size_t)pk.x * F3 + c);
        f16x8 a = sp[0], b8 = sp[1];
        #pragma unroll
        for (int e = 0; e < 8; ++e) {
            acc[e]     += (float)a[e]  * w;
            acc[8 + e] += (float)b8[e] * w;
        }
    }
    float4* op = (float4*)(out + (size_t)i * F3 + c);
    #pragma unroll
    for (int q = 0; q < 4; ++q) {
        float4 v;
        v.x = acc[q * 4 + 0]; v.y = acc[q * 4 + 1]; v.z = acc[q * 4 + 2]; v.w = acc[q * 4 + 3];
        op[q] = v;
    }
}

__global__ void k_fixB(const _Float16* __restrict__ g, const float* __restrict__ dinv,
                       const int* __restrict__ ovf_n, const int* __restrict__ ovf, int ovf_cap,
                       float* __restrict__ out) {
    int n = *ovf_n; if (n > ovf_cap) n = ovf_cap;
    for (int j = blockIdx.x * blockDim.x + threadIdx.x; j < n; j += gridDim.x * blockDim.x) {
        int s = ovf[3 * j], d = ovf[3 * j + 1];
        float w = __int_as_float(ovf[3 * j + 2]);   // pre-folded by fixA
        for (int f = 0; f < F3; ++f)
            atomicAdd(&out[(size_t)d * F3 + f], (float)g[(size_t)s * F3 + f] * w);
    }
}

// ---------------- launch ----------------

static inline size_t align256(size_t x) { return (x + 255) & ~(size_t)255; }

extern "C" void kernel_launch(void* const* d_in, const int* in_sizes, int n_in,
                              void* d_out, int out_size, void* d_ws, size_t ws_size,
                              hipStream_t stream) {
    const float* x  = (const float*)d_in[0];
    const void*  ei = d_in[1];
    const float* ew = (const float*)d_in[2];
    const float* W1 = (const float*)d_in[3];
    const float* b1 = (const float*)d_in[4];
    const float* W2 = (const float*)d_in[5];
    const float* b2 = (const float*)d_in[6];
    const float* We = (const float*)d_in[7];
    const float* be = (const float*)d_in[8];
    float* out = (float*)d_out;

    int N = in_sizes[0] / NF0;
    int E = in_sizes[2];

    const int OVF_CAP = 131072;              // safety net; ~never used
    const int BIN_STRIDE = 4096;             // Poisson(~2046) per bin; P(>4096) ~ 0
    int n_bins = (N + 255) >> 8;

    char* p = (char*)d_ws;
    auto alloc = [&](size_t bytes) { char* r = p; p += align256(bytes); return r; };
    int*   flag  = (int*)alloc(4);
    // zeroed region: deg[N] | ovf_n | pad | bin_cnt[n_bins*16]
    size_t zints = (size_t)N + 16 + (size_t)n_bins * 16;
    int*   zreg  = (int*)alloc(zints * 4);
    float* deg   = (float*)zreg;             // becomes dinv after k_binB1
    int*   ovf_n = zreg + N;
    int*   bin_cnt = zreg + N + 16;
    int*   cnt   = (int*)  alloc((size_t)N * 4);
    int*   ovf   = (int*)  alloc((size_t)OVF_CAP * 12);
    int2*  bins  = (int2*) alloc((size_t)n_bins * BIN_STRIDE * 8);
    float* xp    = (float*)alloc((size_t)N * 8 * 4);
    float* agg1  = (float*)alloc((size_t)N * NF0 * 4);
    float* bc    = (float*)alloc((size_t)F3 * 4);
    _Float16* Bh = (_Float16*)alloc((size_t)50 * 64 * 8 * 2);
    _Float16* g  = (_Float16*)alloc((size_t)N * F3 * 2);

    // adaptive bucket capacity (8 B/slot); 24 => Poisson(8) overflow ~1e-6/node
    size_t used = (size_t)(p - (char*)d_ws);
    int cap = 24;
    if (ws_size > used) {
        size_t avail = (ws_size - used) / ((size_t)N * 8);
        if (avail < (size_t)cap) cap = (int)avail;
    } else cap = 4;
    if (cap < 4) cap = 4;
    int2* bucket = (int2*)alloc((size_t)N * cap * 8);

    int eb  = (E + 255) / 256;
    int padxB = (N * 8 + 255) / 256;

    hipMemsetAsync(zreg, 0, zints * 4, stream);
    k_prep<<<padxB + 15, 256, 0, stream>>>(x, xp, N, padxB, W2, We, Bh, b2, be, bc,
                                           (const unsigned int*)ei, E, flag);

    k_binA<<<eb, 256, 0, stream>>>(ei, ew, flag, bin_cnt, bins, BIN_STRIDE, ovf_n, ovf, OVF_CAP, E);
    k_fixdeg<<<16, 256, 0, stream>>>(ovf_n, ovf, OVF_CAP, deg);
    k_binB1<<<n_bins, 256, 0, stream>>>(bins, BIN_STRIDE, bin_cnt, deg, N);
    k_binB2<<<n_bins, 256, 0, stream>>>(bins, BIN_STRIDE, bin_cnt, deg, xp, cnt, bucket, cap,
                                        agg1, ovf_n, ovf, OVF_CAP, N);
    k_fixA<<<16, 256, 0, stream>>>(x, deg, ovf_n, ovf, OVF_CAP, agg1);

    k_node<<<(N + 63) / 64, 256, 0, stream>>>(agg1, W1, b1, Bh, g, N);
    k_aggB<<<(5 * N + 255) / 256, 256, 0, stream>>>(g, deg, bc, cnt, bucket, cap, out, N);
    k_fixB<<<16, 256, 0, stream>>>(g, deg, ovf_n, ovf, OVF_CAP, out);
}

// Round 8
// 182.541 us; speedup vs baseline: 7.1384x; 1.0370x over previous
//
#include <hip/hip_runtime.h>

#define NF0 5
#define F1 320
#define F2 160
#define F3 80
#define NSUB 8          // XCD-local sub-bins (blockIdx & 7 proxy)
#define SUBCAP 512      // slots per (bin,sub); mean occupancy ~256

typedef float f32x4 __attribute__((ext_vector_type(4)));
typedef _Float16 f16x8 __attribute__((ext_vector_type(8)));

// ---------------- prep: zero cursors; pad x -> xp[N][8]; f16 B-frags of W2@We; bc; detect ----------------
// Fragment (kk, ct): lane l holds B[32*kk + 8*(l>>4) + i][16*ct + (l&15)], i=0..7.

__global__ void k_prep(const float* __restrict__ x, float* __restrict__ xp, int N,
                       int padz, int* __restrict__ zreg, int zwords, int padxB,
                       const float* __restrict__ W2, const float* __restrict__ We,
                       _Float16* __restrict__ Bh,
                       const float* __restrict__ b2, const float* __restrict__ be,
                       float* __restrict__ bc,
                       const unsigned int* __restrict__ ei32, int E, int* __restrict__ flag) {
    __shared__ int ok;
    int b = blockIdx.x;
    if (b < padz) {
        int t = b * 256 + threadIdx.x;
        if (t < zwords) zreg[t] = 0;
        return;
    }
    b -= padz;
    if (b < padxB) {
        int t = b * 256 + threadIdx.x;
        if (t < N * 8) {
            int f = t & 7, i = t >> 3;
            xp[t] = (f < NF0) ? x[i * NF0 + f] : 0.f;
        }
    } else if (b < padxB + 13) {
        int t = (b - padxB) * 256 + threadIdx.x;
        if (t >= 50 * 64) return;
        int fid = t >> 6, lane = t & 63;
        int kk = fid / 5, ct = fid % 5;
        int col = ct * 16 + (lane & 15);
        int row0 = kk * 32 + (lane >> 4) * 8;
        float acc[8] = {0.f, 0.f, 0.f, 0.f, 0.f, 0.f, 0.f, 0.f};
        for (int m = 0; m < F2; ++m) {
            float wv = We[m * F3 + col];
            #pragma unroll
            for (int i = 0; i < 8; ++i)
                acc[i] += W2[(size_t)(row0 + i) * F2 + m] * wv;
        }
        size_t ob = (size_t)t * 8;
        #pragma unroll
        for (int i = 0; i < 8; ++i)
            Bh[ob + i] = (_Float16)acc[i];   // RNE
    } else if (b == padxB + 13) {
        int j = threadIdx.x;
        if (j < F3) {
            float s = be[j];
            for (int k = 0; k < F2; ++k) s += b2[k] * We[k * F3 + j];
            bc[j] = s;
        }
    } else {
        if (threadIdx.x == 0) ok = 1;
        __syncthreads();
        int npairs = E < 2048 ? E : 2048;
        for (int i = threadIdx.x; i < npairs; i += blockDim.x)
            if (ei32[2 * i + 1] != 0u) ok = 0;   // benign race
        __syncthreads();
        if (threadIdx.x == 0) *flag = ok;        // 1 => int64 storage, 0 => int32
    }
}

// ---------------- binA: bin edges by dst>>8, XCD-local sub-cursor/sub-region ----------------
// payload: {src | (dst&255)<<24, raw ew}. Requires src < 2^24 (N=100000 ok).
// cursor (sub*n_bins+b): all lines of a (bin,sub) region touched by ONE XCD.

__global__ void k_binA(const void* ei, const float* __restrict__ ew, const int* __restrict__ flag,
                       int* __restrict__ bin_cnt /*stride 4 ints*/, int2* __restrict__ bins,
                       int n_bins, int* __restrict__ ovf_n, int* __restrict__ ovf,
                       int ovf_cap, int E) {
    int e = blockIdx.x * blockDim.x + threadIdx.x;
    if (e >= E) return;
    int sub = blockIdx.x & (NSUB - 1);
    int s, d;
    if (*flag) {
        const long long* p = (const long long*)ei;
        s = (int)p[e]; d = (int)p[E + e];
    } else {
        const int* p = (const int*)ei;
        s = p[e]; d = p[E + e];
    }
    float w = ew[e];
    int b = d >> 8;
    int pos = atomicAdd(&bin_cnt[(sub * n_bins + b) * 4], 1);
    if (pos < SUBCAP) {
        int2 pk;
        pk.x = s | ((d & 255) << 24);
        pk.y = __float_as_int(w);
        bins[(size_t)b * (NSUB * SUBCAP) + sub * SUBCAP + pos] = pk;
    } else {
        int o = atomicAdd(ovf_n, 1);
        if (o < ovf_cap) {
            ovf[3 * o] = s; ovf[3 * o + 1] = d; ovf[3 * o + 2] = __float_as_int(w);
        }
    }
}

// ---------------- binB1: per-bin LDS degree -> dinv; scale xp' = xp * dinv ----------------
// Also folds binA-overflow ew (range-filtered scan; empty in practice).

__global__ __launch_bounds__(256) void k_binB1(const int2* __restrict__ bins,
                                               const int* __restrict__ bin_cnt, int n_bins,
                                               float* __restrict__ dinv, float* __restrict__ xp,
                                               const int* __restrict__ ovf_n,
                                               const int* __restrict__ ovf, int ovf_cap, int N) {
    __shared__ float deg_l[256];
    int b = blockIdx.x, t = threadIdx.x;
    deg_l[t] = 0.f;
    __syncthreads();
    for (int sub = 0; sub < NSUB; ++sub) {
        int ne = bin_cnt[(sub * n_bins + b) * 4]; if (ne > SUBCAP) ne = SUBCAP;
        const int2* bp = bins + (size_t)b * (NSUB * SUBCAP) + sub * SUBCAP;
        for (int j = t; j < ne; j += 256) {
            int2 pk = bp[j];
            atomicAdd(&deg_l[((unsigned int)pk.x) >> 24], __int_as_float(pk.y));
        }
    }
    int n = *ovf_n; if (n > ovf_cap) n = ovf_cap;
    int lo = b * 256;
    for (int j = t; j < n; j += 256) {
        int d = ovf[3 * j + 1];
        if (d >= lo && d < lo + 256)
            atomicAdd(&deg_l[d - lo], __int_as_float(ovf[3 * j + 2]));
    }
    __syncthreads();
    int node = lo + t;
    if (node < N) {
        float di = rsqrtf(1.0f + deg_l[t]);
        dinv[node] = di;
        float4* xr = (float4*)(xp + (size_t)node * 8);
        float4 v0 = xr[0], v1 = xr[1];
        v0.x *= di; v0.y *= di; v0.z *= di; v0.w *= di;
        v1.x *= di; v1.y *= di; v1.z *= di; v1.w *= di;
        xr[0] = v0; xr[1] = v1;
    }
}

// ---------------- binB2: bucket scatter {s, raw ew} + conv1 aggregate in LDS ----------------
// conv1: agg1[d] = dinv[d] * (sum_e ew*xp'[s] + xp'[d]).  binA-ovf edges folded via
// range-filtered scan (snapshot taken before this block pushes anything).

__global__ __launch_bounds__(256) void k_binB2(const int2* __restrict__ bins,
                                               const int* __restrict__ bin_cnt, int n_bins,
                                               const float* __restrict__ dinv,
                                               const float* __restrict__ xp,
                                               int* __restrict__ cnt, int2* __restrict__ bucket,
                                               int cap, float* __restrict__ agg1,
                                               int* __restrict__ ovf_n, int* __restrict__ ovf,
                                               int ovf_cap, int N) {
    __shared__ int cnt_l[256];
    __shared__ float acc_l[256 * NF0];
    int b = blockIdx.x, t = threadIdx.x;
    cnt_l[t] = 0;
    for (int q = t; q < 256 * NF0; q += 256) acc_l[q] = 0.f;
    int nsnap = *ovf_n; if (nsnap > ovf_cap) nsnap = ovf_cap;
    __syncthreads();
    int lo = b * 256;

    // binA-overflow conv1 contributions for this block's range (normally empty)
    for (int j = t; j < nsnap; j += 256) {
        int d = ovf[3 * j + 1];
        if (d >= lo && d < lo + 256) {
            int s = ovf[3 * j];
            float w = __int_as_float(ovf[3 * j + 2]);
            float4 sv = *(const float4*)(xp + (size_t)s * 8);
            float s4 = xp[(size_t)s * 8 + 4];
            int dl = d - lo;
            atomicAdd(&acc_l[dl * NF0 + 0], sv.x * w);
            atomicAdd(&acc_l[dl * NF0 + 1], sv.y * w);
            atomicAdd(&acc_l[dl * NF0 + 2], sv.z * w);
            atomicAdd(&acc_l[dl * NF0 + 3], sv.w * w);
            atomicAdd(&acc_l[dl * NF0 + 4], s4 * w);
        }
    }

    for (int sub = 0; sub < NSUB; ++sub) {
        int ne = bin_cnt[(sub * n_bins + b) * 4]; if (ne > SUBCAP) ne = SUBCAP;
        const int2* bp = bins + (size_t)b * (NSUB * SUBCAP) + sub * SUBCAP;
        for (int j = t; j < ne; j += 256) {
            int2 pk = bp[j];
            int s = pk.x & 0xFFFFFF;
            int dl = ((unsigned int)pk.x) >> 24;
            float w = __int_as_float(pk.y);
            int node = lo + dl;
            int pos = atomicAdd(&cnt_l[dl], 1);
            if (pos < cap) {
                int2 out_pk; out_pk.x = s; out_pk.y = pk.y;   // raw ew
                bucket[(size_t)node * cap + pos] = out_pk;
            } else {
                int o = atomicAdd(ovf_n, 1);
                if (o < ovf_cap) { ovf[3 * o] = s; ovf[3 * o + 1] = node; ovf[3 * o + 2] = pk.y; }
            }
            float4 sv = *(const float4*)(xp + (size_t)s * 8);
            float s4 = xp[(size_t)s * 8 + 4];
            atomicAdd(&acc_l[dl * NF0 + 0], sv.x * w);
            atomicAdd(&acc_l[dl * NF0 + 1], sv.y * w);
            atomicAdd(&acc_l[dl * NF0 + 2], sv.z * w);
            atomicAdd(&acc_l[dl * NF0 + 3], sv.w * w);
            atomicAdd(&acc_l[dl * NF0 + 4], s4 * w);
        }
    }
    __syncthreads();

    int node = lo + t;
    if (node < N) {
        float di = dinv[node];
        float4 xv = *(const float4*)(xp + (size_t)node * 8);
        float x4 = xp[(size_t)node * 8 + 4];
        float* op = agg1 + (size_t)node * NF0;
        op[0] = di * (acc_l[t * NF0 + 0] + xv.x);
        op[1] = di * (acc_l[t * NF0 + 1] + xv.y);
        op[2] = di * (acc_l[t * NF0 + 2] + xv.z);
        op[3] = di * (acc_l[t * NF0 + 3] + xv.w);
        op[4] = di * (acc_l[t * NF0 + 4] + x4);
        int c = cnt_l[t]; if (c > cap) c = cap;
        cnt[node] = c;
    }
}

// ---------------- fused node transform via MFMA (f16 2-product); g' = g * dinv ----------------
// Block 256 = 4 waves; one set of 16 nodes per wave. W1+b1 in LDS.
// D: col=lane&15, row=(lane>>4)*4+reg. g' stored as f16 (RNE).

__global__ __launch_bounds__(256) void k_node(const float* __restrict__ agg1,
                                              const float* __restrict__ W1,
                                              const float* __restrict__ b1,
                                              const _Float16* __restrict__ Bh,
                                              const float* __restrict__ dinv,
                                              _Float16* __restrict__ g, int N) {
    __shared__ float W_l[6 * F1];   // W1 rows then b1
    int tid = threadIdx.x;
    for (int i = tid; i < 480; i += 256) {
        float4 v = (i < 400) ? ((const float4*)W1)[i] : ((const float4*)b1)[i - 400];
        ((float4*)W_l)[i] = v;
    }
    __syncthreads();

    int w = tid >> 6, l = tid & 63;
    int nl = l & 15, kg = l >> 4;
    int base = blockIdx.x * 64 + w * 16;
    int n0 = base + nl;

    float a0v[5] = {0.f, 0.f, 0.f, 0.f, 0.f};
    if (n0 < N) {
        const float* ap = agg1 + (size_t)n0 * NF0;
        #pragma unroll
        for (int j = 0; j < 5; ++j) a0v[j] = ap[j];
    }

    f32x4 zero = {0.f, 0.f, 0.f, 0.f};
    f32x4 acc[5] = {zero, zero, zero, zero, zero};
    const f16x8* bhp = (const f16x8*)Bh;

    #pragma unroll
    for (int kk = 0; kk < 10; ++kk) {
        int k0 = kk * 32 + kg * 8;
        float v0[8];
        const float* bb = W_l + 5 * F1 + k0;
        #pragma unroll
        for (int i = 0; i < 8; ++i) v0[i] = bb[i];
        #pragma unroll
        for (int j = 0; j < 5; ++j) {
            const float* wp = W_l + j * F1 + k0;
            float aj0 = a0v[j];
            #pragma unroll
            for (int i = 0; i < 8; ++i) v0[i] += aj0 * wp[i];
        }
        f16x8 ah0, al0;
        #pragma unroll
        for (int i = 0; i < 8; ++i) {
            float t0 = fmaxf(v0[i], 0.f);
            _Float16 h0 = (_Float16)t0;
            ah0[i] = h0;
            al0[i] = (_Float16)(t0 - (float)h0);
        }
        #pragma unroll
        for (int ct = 0; ct < 5; ++ct) {
            f16x8 bf = bhp[(kk * 5 + ct) * 64 + l];
            acc[ct] = __builtin_amdgcn_mfma_f32_16x16x32_f16(ah0, bf, acc[ct], 0, 0, 0);
            acc[ct] = __builtin_amdgcn_mfma_f32_16x16x32_f16(al0, bf, acc[ct], 0, 0, 0);
        }
    }

    #pragma unroll
    for (int r = 0; r < 4; ++r) {
        int r0 = base + kg * 4 + r;
        if (r0 < N) {
            float dv = dinv[r0];
            #pragma unroll
            for (int ct = 0; ct < 5; ++ct)
                g[(size_t)r0 * F3 + ct * 16 + nl] = (_Float16)(acc[ct][r] * dv);
        }
    }
}

// ---------------- conv2 aggregation via bucket gather (f16 g', raw ew) -> d_out ----------------
// out[d] = dinv[d] * (sum_e ew*g'[s] + g'[d]) + bc.  5 threads/node, 16 cols each.

__global__ __launch_bounds__(256) void k_aggB(const _Float16* __restrict__ g,
                                              const float* __restrict__ dinv,
                                              const float* __restrict__ bc,
                                              const int* __restrict__ cnt,
                                              const int2* __restrict__ bucket, int cap,
                                              float* __restrict__ out, int N) {
    int t = blockIdx.x * blockDim.x + threadIdx.x;
    if (t >= 5 * N) return;
    int i = t / 5;
    int c = (t - i * 5) << 4;    // col base: 0,16,32,48,64
    float acc[16];
    #pragma unroll
    for (int e = 0; e < 16; ++e) acc[e] = 0.f;
    int cn = cnt[i];
    const int2* row = bucket + (size_t)i * cap;
    #pragma unroll 2
    for (int j = 0; j < cn; ++j) {
        int2 pk = row[j];
        float w = __int_as_float(pk.y);      // raw ew (dinv folded into g' and final scale)
        const f16x8* sp = (const f16x8*)(g + (size_t)pk.x * F3 + c);
        f16x8 a = sp[0], b8 = sp[1];
        #pragma unroll
        for (int e = 0; e < 8; ++e) {
            acc[e]     += (float)a[e]  * w;
            acc[8 + e] += (float)b8[e] * w;
        }
    }
    float di = dinv[i];
    const f16x8* sp = (const f16x8*)(g + (size_t)i * F3 + c);
    f16x8 u0 = sp[0], u1 = sp[1];
    const float4* bp = (const float4*)(bc + c);
    float4 q0 = bp[0], q1 = bp[1], q2 = bp[2], q3 = bp[3];
    float4 o0, o1, o2, o3;
    o0.x = di * (acc[0]  + (float)u0[0]) + q0.x;
    o0.y = di * (acc[1]  + (float)u0[1]) + q0.y;
    o0.z = di * (acc[2]  + (float)u0[2]) + q0.z;
    o0.w = di * (acc[3]  + (float)u0[3]) + q0.w;
    o1.x = di * (acc[4]  + (float)u0[4]) + q1.x;
    o1.y = di * (acc[5]  + (float)u0[5]) + q1.y;
    o1.z = di * (acc[6]  + (float)u0[6]) + q1.z;
    o1.w = di * (acc[7]  + (float)u0[7]) + q1.w;
    o2.x = di * (acc[8]  + (float)u1[0]) + q2.x;
    o2.y = di * (acc[9]  + (float)u1[1]) + q2.y;
    o2.z = di * (acc[10] + (float)u1[2]) + q2.z;
    o2.w = di * (acc[11] + (float)u1[3]) + q2.w;
    o3.x = di * (acc[12] + (float)u1[4]) + q3.x;
    o3.y = di * (acc[13] + (float)u1[5]) + q3.y;
    o3.z = di * (acc[14] + (float)u1[6]) + q3.z;
    o3.w = di * (acc[15] + (float)u1[7]) + q3.w;
    float4* op = (float4*)(out + (size_t)i * F3 + c);
    op[0] = o0; op[1] = o1; op[2] = o2; op[3] = o3;
}

// all overflow edges (binA bin-full + binB2 bucket-full): out[d] += dinv[d]*ew*g'[s]
__global__ void k_fixB(const _Float16* __restrict__ g, const float* __restrict__ dinv,
                       const int* __restrict__ ovf_n, const int* __restrict__ ovf, int ovf_cap,
                       float* __restrict__ out) {
    int n = *ovf_n; if (n > ovf_cap) n = ovf_cap;
    for (int j = blockIdx.x * blockDim.x + threadIdx.x; j < n; j += gridDim.x * blockDim.x) {
        int s = ovf[3 * j], d = ovf[3 * j + 1];
        float w = dinv[d] * __int_as_float(ovf[3 * j + 2]);
        for (int f = 0; f < F3; ++f)
            atomicAdd(&out[(size_t)d * F3 + f], (float)g[(size_t)s * F3 + f] * w);
    }
}

// ---------------- launch ----------------

static inline size_t align256(size_t x) { return (x + 255) & ~(size_t)255; }

extern "C" void kernel_launch(void* const* d_in, const int* in_sizes, int n_in,
                              void* d_out, int out_size, void* d_ws, size_t ws_size,
                              hipStream_t stream) {
    const float* x  = (const float*)d_in[0];
    const void*  ei = d_in[1];
    const float* ew = (const float*)d_in[2];
    const float* W1 = (const float*)d_in[3];
    const float* b1 = (const float*)d_in[4];
    const float* W2 = (const float*)d_in[5];
    const float* b2 = (const float*)d_in[6];
    const float* We = (const float*)d_in[7];
    const float* be = (const float*)d_in[8];
    float* out = (float*)d_out;

    int N = in_sizes[0] / NF0;
    int E = in_sizes[2];

    const int OVF_CAP = 131072;              // safety net; ~never used
    int n_bins = (N + 255) >> 8;

    char* p = (char*)d_ws;
    auto alloc = [&](size_t bytes) { char* r = p; p += align256(bytes); return r; };
    int*   flag  = (int*)alloc(4);
    // zeroed-by-prep region: ovf_n | pad | bin_cnt[NSUB*n_bins*4]
    int zwords = 16 + NSUB * n_bins * 4;
    int*   zreg  = (int*)alloc((size_t)zwords * 4);
    int*   ovf_n = zreg;
    int*   bin_cnt = zreg + 16;
    float* dinv  = (float*)alloc((size_t)N * 4);
    int*   cnt   = (int*)  alloc((size_t)N * 4);
    int*   ovf   = (int*)  alloc((size_t)OVF_CAP * 12);
    int2*  bins  = (int2*) alloc((size_t)n_bins * NSUB * SUBCAP * 8);
    float* xp    = (float*)alloc((size_t)N * 8 * 4);
    float* agg1  = (float*)alloc((size_t)N * NF0 * 4);
    float* bc    = (float*)alloc((size_t)F3 * 4);
    _Float16* Bh = (_Float16*)alloc((size_t)50 * 64 * 8 * 2);
    _Float16* g  = (_Float16*)alloc((size_t)N * F3 * 2);

    // adaptive bucket capacity (8 B/slot); 24 => Poisson(8) overflow ~1e-6/node
    size_t used = (size_t)(p - (char*)d_ws);
    int cap = 24;
    if (ws_size > used) {
        size_t avail = (ws_size - used) / ((size_t)N * 8);
        if (avail < (size_t)cap) cap = (int)avail;
    } else cap = 4;
    if (cap < 4) cap = 4;
    int2* bucket = (int2*)alloc((size_t)N * cap * 8);

    int eb    = (E + 255) / 256;
    int padz  = (zwords + 255) / 256;
    int padxB = (N * 8 + 255) / 256;

    k_prep<<<padz + padxB + 15, 256, 0, stream>>>(x, xp, N, padz, zreg, zwords, padxB,
                                                  W2, We, Bh, b2, be, bc,
                                                  (const unsigned int*)ei, E, flag);

    k_binA<<<eb, 256, 0, stream>>>(ei, ew, flag, bin_cnt, bins, n_bins, ovf_n, ovf, OVF_CAP, E);
    k_binB1<<<n_bins, 256, 0, stream>>>(bins, bin_cnt, n_bins, dinv, xp, ovf_n, ovf, OVF_CAP, N);
    k_binB2<<<n_bins, 256, 0, stream>>>(bins, bin_cnt, n_bins, dinv, xp, cnt, bucket, cap,
                                        agg1, ovf_n, ovf, OVF_CAP, N);

    k_node<<<(N + 63) / 64, 256, 0, stream>>>(agg1, W1, b1, Bh, dinv, g, N);
    k_aggB<<<(5 * N + 255) / 256, 256, 0, stream>>>(g, dinv, bc, cnt, bucket, cap, out, N);
    k_fixB<<<16, 256, 0, stream>>>(g, dinv, ovf_n, ovf, OVF_CAP, out);
}